// Round 17
// baseline (1557.328 us; speedup 1.0000x reference)
//
#include <hip/hip_runtime.h>
#include <hip/hip_bf16.h>
#include <math.h>

#define LNUM 4
#define H 16
#define D 1024
#define HS 64
#define DFF 5120
#define V 32000
#define BB 2
#define T 1024
#define M (BB*T)          // 2048 token rows
#define EPS 1e-5f

typedef __attribute__((ext_vector_type(8))) short bf16x8;
typedef __attribute__((ext_vector_type(4))) float f32x4;

// async global->LDS, 16B per lane (wave-uniform LDS base + lane*16)
__device__ __forceinline__ void gload16(const void* g, void* l) {
    __builtin_amdgcn_global_load_lds(
        (const __attribute__((address_space(1))) void*)g,
        (__attribute__((address_space(3))) void*)l, 16, 0, 0);
}

__device__ __forceinline__ float wred_sum(float v) {
    #pragma unroll
    for (int off = 32; off; off >>= 1) v += __shfl_xor(v, off, 64);
    return v;
}

// ---------------------------------------------------------------------------
// embed + first pre-attn LN fused (wave-per-row, 4 rows/block)
// ---------------------------------------------------------------------------
__global__ __launch_bounds__(256) void embed_ln_kernel(const int* __restrict__ idx,
        const float* __restrict__ tok, const float* __restrict__ pos,
        const float* __restrict__ g, const float* __restrict__ b,
        float* __restrict__ x, __hip_bfloat16* __restrict__ xn) {
    int w = threadIdx.x >> 6, lane = threadIdx.x & 63;
    int row = blockIdx.x * 4 + w;
    int t = row & (T - 1);
    int tok_id = idx[row];
    const float* tp = tok + (size_t)tok_id * D;
    const float* pp = pos + (size_t)t * D;
    float4 xv[4];
    float s = 0.f;
    #pragma unroll
    for (int c = 0; c < 4; ++c) {
        int j = c * 256 + lane * 4;
        float4 a = *(const float4*)&tp[j];
        float4 p = *(const float4*)&pp[j];
        a.x += p.x; a.y += p.y; a.z += p.z; a.w += p.w;
        *(float4*)&x[(size_t)row * D + j] = a;
        xv[c] = a;
        s += a.x + a.y + a.z + a.w;
    }
    float mu = wred_sum(s) * (1.0f / D);
    float vs = 0.f;
    #pragma unroll
    for (int c = 0; c < 4; ++c) {
        xv[c].x -= mu; xv[c].y -= mu; xv[c].z -= mu; xv[c].w -= mu;
        vs += xv[c].x*xv[c].x + xv[c].y*xv[c].y + xv[c].z*xv[c].z + xv[c].w*xv[c].w;
    }
    float rs = rsqrtf(wred_sum(vs) * (1.0f / D) + EPS);
    #pragma unroll
    for (int c = 0; c < 4; ++c) {
        int j = c * 256 + lane * 4;
        float4 gv = *(const float4*)&g[j];
        float4 bv = *(const float4*)&b[j];
        union { ushort4 u4; __hip_bfloat16 h[4]; } pk;
        pk.h[0] = __float2bfloat16(xv[c].x * rs * gv.x + bv.x);
        pk.h[1] = __float2bfloat16(xv[c].y * rs * gv.y + bv.y);
        pk.h[2] = __float2bfloat16(xv[c].z * rs * gv.z + bv.z);
        pk.h[3] = __float2bfloat16(xv[c].w * rs * gv.w + bv.w);
        *(ushort4*)&xn[(size_t)row * D + j] = pk.u4;
    }
}

// ---------------------------------------------------------------------------
// proj tail, fused: x2 = x + p0 + p1 + bp ; xn = ln(x2, n2) -> bf16
// ---------------------------------------------------------------------------
__global__ __launch_bounds__(256) void proj_tail_kernel(
        const float* __restrict__ part, const float* __restrict__ bp,
        const float* __restrict__ res,
        const float* __restrict__ g, const float* __restrict__ b,
        float* __restrict__ x2out, __hip_bfloat16* __restrict__ xnout) {
    const size_t MD = (size_t)M * D;
    int w = threadIdx.x >> 6, lane = threadIdx.x & 63;
    int row = blockIdx.x * 4 + w;
    size_t ro = (size_t)row * D;
    float4 f[4];
    float s = 0.f;
    #pragma unroll
    for (int c = 0; c < 4; ++c) {
        int j = c * 256 + lane * 4;
        float4 rv = *(const float4*)&res[ro + j];
        float4 p0 = *(const float4*)&part[ro + j];
        float4 p1 = *(const float4*)&part[MD + ro + j];
        float4 bv = *(const float4*)&bp[j];
        float4 a;
        a.x = rv.x + p0.x + p1.x + bv.x;
        a.y = rv.y + p0.y + p1.y + bv.y;
        a.z = rv.z + p0.z + p1.z + bv.z;
        a.w = rv.w + p0.w + p1.w + bv.w;
        *(float4*)&x2out[ro + j] = a;
        f[c] = a;
        s += a.x + a.y + a.z + a.w;
    }
    float mu = wred_sum(s) * (1.0f / D);
    float vs = 0.f;
    #pragma unroll
    for (int c = 0; c < 4; ++c) {
        f[c].x -= mu; f[c].y -= mu; f[c].z -= mu; f[c].w -= mu;
        vs += f[c].x*f[c].x + f[c].y*f[c].y + f[c].z*f[c].z + f[c].w*f[c].w;
    }
    float rs = rsqrtf(wred_sum(vs) * (1.0f / D) + EPS);
    #pragma unroll
    for (int c = 0; c < 4; ++c) {
        int j = c * 256 + lane * 4;
        float4 gv = *(const float4*)&g[j];
        float4 bv = *(const float4*)&b[j];
        union { ushort4 u4; __hip_bfloat16 h[4]; } pk;
        pk.h[0] = __float2bfloat16(f[c].x * rs * gv.x + bv.x);
        pk.h[1] = __float2bfloat16(f[c].y * rs * gv.y + bv.y);
        pk.h[2] = __float2bfloat16(f[c].z * rs * gv.z + bv.z);
        pk.h[3] = __float2bfloat16(f[c].w * rs * gv.w + bv.w);
        *(ushort4*)&xnout[ro + j] = pk.u4;
    }
}

// ---------------------------------------------------------------------------
// FFN tail, fused:  f = sum(partials)+b2 ; x = res + ln(ln(f,g1,b1),g2,b2g)
// then xn = ln(x, gn, bn) -> bf16
// ---------------------------------------------------------------------------
template<int NP>
__global__ __launch_bounds__(256) void ffn_tail_kernel(
        const float* __restrict__ part, const float* __restrict__ b2,
        const float* __restrict__ g1, const float* __restrict__ b1,
        const float* __restrict__ g2, const float* __restrict__ b2g,
        const float* __restrict__ res, float* __restrict__ xout,
        const float* __restrict__ gn, const float* __restrict__ bn,
        __hip_bfloat16* __restrict__ xnout) {
    const size_t MD = (size_t)M * D;
    int w = threadIdx.x >> 6, lane = threadIdx.x & 63;
    int row = blockIdx.x * 4 + w;
    size_t ro = (size_t)row * D;
    float4 f[4];
    float s = 0.f;
    #pragma unroll
    for (int c = 0; c < 4; ++c) {
        int j = c * 256 + lane * 4;
        float4 acc = *(const float4*)&b2[j];
        #pragma unroll
        for (int pI = 0; pI < NP; ++pI) {
            float4 pv = *(const float4*)&part[pI * MD + ro + j];
            acc.x += pv.x; acc.y += pv.y; acc.z += pv.z; acc.w += pv.w;
        }
        f[c] = acc;
        s += acc.x + acc.y + acc.z + acc.w;
    }
    float mu = wred_sum(s) * (1.0f / D);
    float vs = 0.f;
    #pragma unroll
    for (int c = 0; c < 4; ++c) {
        f[c].x -= mu; f[c].y -= mu; f[c].z -= mu; f[c].w -= mu;
        vs += f[c].x*f[c].x + f[c].y*f[c].y + f[c].z*f[c].z + f[c].w*f[c].w;
    }
    float rs = rsqrtf(wred_sum(vs) * (1.0f / D) + EPS);
    float s2 = 0.f;
    #pragma unroll
    for (int c = 0; c < 4; ++c) {
        int j = c * 256 + lane * 4;
        float4 gv = *(const float4*)&g1[j];
        float4 bv = *(const float4*)&b1[j];
        f[c].x = f[c].x * rs * gv.x + bv.x;
        f[c].y = f[c].y * rs * gv.y + bv.y;
        f[c].z = f[c].z * rs * gv.z + bv.z;
        f[c].w = f[c].w * rs * gv.w + bv.w;
        s2 += f[c].x + f[c].y + f[c].z + f[c].w;
    }
    float mu2 = wred_sum(s2) * (1.0f / D);
    float vs2 = 0.f;
    #pragma unroll
    for (int c = 0; c < 4; ++c) {
        f[c].x -= mu2; f[c].y -= mu2; f[c].z -= mu2; f[c].w -= mu2;
        vs2 += f[c].x*f[c].x + f[c].y*f[c].y + f[c].z*f[c].z + f[c].w*f[c].w;
    }
    float rs2 = rsqrtf(wred_sum(vs2) * (1.0f / D) + EPS);
    float s3 = 0.f;
    #pragma unroll
    for (int c = 0; c < 4; ++c) {
        int j = c * 256 + lane * 4;
        float4 gv = *(const float4*)&g2[j];
        float4 bv = *(const float4*)&b2g[j];
        float4 rv = *(const float4*)&res[ro + j];
        f[c].x = rv.x + f[c].x * rs2 * gv.x + bv.x;
        f[c].y = rv.y + f[c].y * rs2 * gv.y + bv.y;
        f[c].z = rv.z + f[c].z * rs2 * gv.z + bv.z;
        f[c].w = rv.w + f[c].w * rs2 * gv.w + bv.w;
        *(float4*)&xout[ro + j] = f[c];
        s3 += f[c].x + f[c].y + f[c].z + f[c].w;
    }
    float mu3 = wred_sum(s3) * (1.0f / D);
    float vs3 = 0.f;
    #pragma unroll
    for (int c = 0; c < 4; ++c) {
        f[c].x -= mu3; f[c].y -= mu3; f[c].z -= mu3; f[c].w -= mu3;
        vs3 += f[c].x*f[c].x + f[c].y*f[c].y + f[c].z*f[c].z + f[c].w*f[c].w;
    }
    float rs3 = rsqrtf(wred_sum(vs3) * (1.0f / D) + EPS);
    #pragma unroll
    for (int c = 0; c < 4; ++c) {
        int j = c * 256 + lane * 4;
        float4 gv = *(const float4*)&gn[j];
        float4 bv = *(const float4*)&bn[j];
        union { ushort4 u4; __hip_bfloat16 h[4]; } pk;
        pk.h[0] = __float2bfloat16(f[c].x * rs3 * gv.x + bv.x);
        pk.h[1] = __float2bfloat16(f[c].y * rs3 * gv.y + bv.y);
        pk.h[2] = __float2bfloat16(f[c].z * rs3 * gv.z + bv.z);
        pk.h[3] = __float2bfloat16(f[c].w * rs3 * gv.w + bv.w);
        *(ushort4*)&xnout[ro + j] = pk.u4;
    }
}

// ---------------------------------------------------------------------------
// tiled transpose + fp32->bf16: in [R][C] f32 -> out [C][R] bf16 (Wfin)
// ---------------------------------------------------------------------------
__global__ __launch_bounds__(256) void transpose_bf16_kernel(
        const float* __restrict__ in, __hip_bfloat16* __restrict__ out,
        int R, int C) {
    __shared__ float t[32][33];
    int tx = threadIdx.x & 31, ty = threadIdx.x >> 5;
    int c0 = blockIdx.x * 32, r0 = blockIdx.y * 32;
    #pragma unroll
    for (int i = 0; i < 4; ++i)
        t[ty + i * 8][tx] = in[(size_t)(r0 + ty + i * 8) * C + c0 + tx];
    __syncthreads();
    #pragma unroll
    for (int i = 0; i < 4; ++i)
        out[(size_t)(c0 + ty + i * 8) * R + r0 + tx] = __float2bfloat16(t[tx][ty + i * 8]);
}

// ---------------------------------------------------------------------------
// per-LAYER weight prep (both halves) in ONE launch: grid (32, 32, 8)
// ---------------------------------------------------------------------------
__global__ __launch_bounds__(256) void trans_qkvp2_kernel(
        const float* __restrict__ Wq0, const float* __restrict__ Wk0,
        const float* __restrict__ Wv0, const float* __restrict__ Wp0,
        const float* __restrict__ Wq1, const float* __restrict__ Wk1,
        const float* __restrict__ Wv1, const float* __restrict__ Wp1,
        short* __restrict__ qkvT, short* __restrict__ WpT) {
    __shared__ float t[32][33];
    int tx = threadIdx.x & 31, ty = threadIdx.x >> 5;
    int z = blockIdx.z;
    int half = z >> 2, which = z & 3;
    const float* in;
    __hip_bfloat16* out;
    int inC, outC, c0;
    int r0 = blockIdx.y * 32;
    if (which < 3) {
        int c0g = blockIdx.x * 32;
        int h = c0g >> 6;
        c0 = c0g & 63;
        const float* base = which == 0 ? (half ? Wq1 : Wq0)
                          : which == 1 ? (half ? Wk1 : Wk0)
                                       : (half ? Wv1 : Wv0);
        in = base + (size_t)h * D * HS;
        out = (__hip_bfloat16*)qkvT + (size_t)half * 3 * H * HS * D
            + ((size_t)which * H + h) * HS * D;
        inC = HS; outC = D;
    } else {
        c0 = blockIdx.x * 32;
        in = half ? Wp1 : Wp0;
        out = (__hip_bfloat16*)WpT + (size_t)half * D * D;
        inC = D; outC = D;
    }
    #pragma unroll
    for (int i = 0; i < 4; ++i)
        t[ty + i * 8][tx] = in[(size_t)(r0 + ty + i * 8) * inC + c0 + tx];
    __syncthreads();
    #pragma unroll
    for (int i = 0; i < 4; ++i)
        out[(size_t)(c0 + ty + i * 8) * outC + r0 + tx] = __float2bfloat16(t[tx][ty + i * 8]);
}

// ---------------------------------------------------------------------------
// per-layer W1+W2 transpose in ONE launch: grid (160, 32, 2)
// ---------------------------------------------------------------------------
__global__ __launch_bounds__(256) void trans_w12_kernel(
        const float* __restrict__ W1, const float* __restrict__ W2,
        short* __restrict__ W1T, short* __restrict__ W2T) {
    __shared__ float t[32][33];
    int tx = threadIdx.x & 31, ty = threadIdx.x >> 5;
    int z = blockIdx.z;
    const float* in; __hip_bfloat16* out;
    int inC, outC, r0, c0;
    if (z == 0) { in = W1; out = (__hip_bfloat16*)W1T; inC = DFF; outC = D;
                  r0 = blockIdx.y * 32; c0 = blockIdx.x * 32; }
    else        { in = W2; out = (__hip_bfloat16*)W2T; inC = D; outC = DFF;
                  r0 = blockIdx.x * 32; c0 = blockIdx.y * 32; }
    #pragma unroll
    for (int i = 0; i < 4; ++i)
        t[ty + i * 8][tx] = in[(size_t)(r0 + ty + i * 8) * inC + c0 + tx];
    __syncthreads();
    #pragma unroll
    for (int i = 0; i < 4; ++i)
        out[(size_t)(c0 + ty + i * 8) * outC + r0 + tx] = __float2bfloat16(t[tx][ty + i * 8]);
}

// ---------------------------------------------------------------------------
// bf16->bf16 transpose for V: in [T][HS] per bh -> out [HS][T]
// ---------------------------------------------------------------------------
__global__ __launch_bounds__(256) void transpose_v_kernel(const short* __restrict__ in,
        short* __restrict__ out) {
    __shared__ short t[32][33];
    int z = blockIdx.z;
    in  += (size_t)z * T * HS;
    out += (size_t)z * HS * T;
    int tx = threadIdx.x & 31, ty = threadIdx.x >> 5;
    int c0 = blockIdx.x * 32, r0 = blockIdx.y * 32;
    #pragma unroll
    for (int i = 0; i < 4; ++i)
        t[ty + i * 8][tx] = in[(size_t)(r0 + ty + i * 8) * HS + c0 + tx];
    __syncthreads();
    #pragma unroll
    for (int i = 0; i < 4; ++i)
        out[(size_t)(c0 + ty + i * 8) * T + r0 + tx] = t[tx][ty + i * 8];
}

// ---------------------------------------------------------------------------
// 256x256 bf16 MFMA GEMM, 2 phases per K-tile (BK=64). 512 thr = 8 waves.
// EPI: 0 f32+bias -> C0 ; 2 leaky -> bf16 Cbf.  M fixed = 2048 (8 M-tiles).
// ---------------------------------------------------------------------------
template<int EPI>
__global__ __launch_bounds__(512, 2) void mm256_kernel(
        const short* __restrict__ A, const short* __restrict__ BT,
        const float* __restrict__ bias0, float* __restrict__ C0,
        __hip_bfloat16* __restrict__ Cbf, int N, int Kloop, int lda) {
    __shared__ __align__(16) char LA[2][2][256 * 64];
    __shared__ __align__(16) char LB[2][2][256 * 64];
    int tid = threadIdx.x;
    int lane = tid & 63, wid = tid >> 6;
    int wr = wid >> 2, wc = wid & 3;
    int l15 = lane & 15, l16 = lane >> 4;

    int nwg = gridDim.x;
    int bid = blockIdx.x;
    int q = nwg >> 3, r = nwg & 7;
    int xcd = bid & 7, loc = bid >> 3;
    int wg = (xcd < r ? xcd * (q + 1) : r * (q + 1) + (xcd - r) * q) + loc;
    int m0 = (wg & 7) * 256;
    int n0 = (wg >> 3) * 256;

    const size_t lda2 = (size_t)lda * 2;
    const char* Agc = (const char*)A + (size_t)m0 * lda2;
    const char* Bgc = (const char*)BT + (size_t)n0 * lda2;

    f32x4 acc[8][4] = {};
    bf16x8 af[8], bfr[4];

    auto stA = [&](int buf, int kh, int kt) {
        #pragma unroll
        for (int i = 0; i < 2; ++i) {
            int o = i * 8192 + tid * 16;
            int row = o >> 6, col = o & 63;
            gload16(Agc + (size_t)row * lda2 + kt * 128 + kh * 64 +
                    (col ^ (((row >> 1) & 3) << 4)), LA[buf][kh] + o);
        }
    };
    auto stB = [&](int buf, int kh, int kt) {
        #pragma unroll
        for (int i = 0; i < 2; ++i) {
            int o = i * 8192 + tid * 16;
            int row = o >> 6, col = o & 63;
            gload16(Bgc + (size_t)row * lda2 + kt * 128 + kh * 64 +
                    (col ^ (((row >> 1) & 3) << 4)), LB[buf][kh] + o);
        }
    };
    auto rdA = [&](int buf, int kk) {
        #pragma unroll
        for (int mf = 0; mf < 8; ++mf) {
            int row = wr * 128 + mf * 16 + l15;
            af[mf] = *(const bf16x8*)(LA[buf][kk] + row * 64 +
                      ((l16 * 16) ^ (((row >> 1) & 3) << 4)));
        }
    };
    auto rdB4 = [&](int buf, int kk) {
        #pragma unroll
        for (int nf = 0; nf < 4; ++nf) {
            int row = wc * 64 + nf * 16 + l15;
            bfr[nf] = *(const bf16x8*)(LB[buf][kk] + row * 64 +
                       ((l16 * 16) ^ (((row >> 1) & 3) << 4)));
        }
    };
    auto mfma32 = [&]() {
        __builtin_amdgcn_s_setprio(1);
        #pragma unroll
        for (int mf = 0; mf < 8; ++mf)
            #pragma unroll
            for (int nf = 0; nf < 4; ++nf)
                acc[mf][nf] = __builtin_amdgcn_mfma_f32_16x16x32_bf16(
                    af[mf], bfr[nf], acc[mf][nf], 0, 0, 0);
        __builtin_amdgcn_s_setprio(0);
    };

    const int NT = Kloop / 64;
    stA(0, 0, 0); stB(0, 0, 0); stA(0, 1, 0); stB(0, 1, 0);
    stA(1, 0, 1); stB(1, 0, 1);
    asm volatile("s_waitcnt vmcnt(4)" ::: "memory");
    __builtin_amdgcn_sched_barrier(0);
    __builtin_amdgcn_s_barrier();
    __builtin_amdgcn_sched_barrier(0);

    for (int t = 0; t < NT; ++t) {
        int buf = t & 1;
        rdA(buf, 0); rdB4(buf, 0);
        if (t + 1 < NT) { stA(buf ^ 1, 1, t + 1); stB(buf ^ 1, 1, t + 1); }
        mfma32();
        __builtin_amdgcn_sched_barrier(0);
        __builtin_amdgcn_s_barrier();
        __builtin_amdgcn_sched_barrier(0);
        rdA(buf, 1); rdB4(buf, 1);
        if (t + 2 < NT) { stA(buf, 0, t + 2); stB(buf, 0, t + 2); }
        mfma32();
        if (t + 2 < NT) { asm volatile("s_waitcnt vmcnt(4)" ::: "memory"); }
        else            { asm volatile("s_waitcnt vmcnt(0)" ::: "memory"); }
        __builtin_amdgcn_sched_barrier(0);
        __builtin_amdgcn_s_barrier();
        __builtin_amdgcn_sched_barrier(0);
    }

    #pragma unroll
    for (int mf = 0; mf < 8; ++mf) {
        #pragma unroll
        for (int nf = 0; nf < 4; ++nf) {
            int col = n0 + wc * 64 + nf * 16 + l15;
            float bv = bias0[col];
            #pragma unroll
            for (int rr = 0; rr < 4; ++rr) {
                int row = m0 + wr * 128 + mf * 16 + l16 * 4 + rr;
                float v = acc[mf][nf][rr] + bv;
                if (EPI == 0) {
                    C0[(size_t)row * N + col] = v;
                } else {
                    v = v > 0.f ? v : 0.01f * v;
                    Cbf[(size_t)row * N + col] = __float2bfloat16(v);
                }
            }
        }
    }
}

// ---------------------------------------------------------------------------
// bf16 MFMA GEMM (128-tile, double-buffered counted-vmcnt) — qkv/proj/W1/W2.
// EPI: 0 f32 C0 ; 1 +res f32 C0 ; 2 leaky bf16 Cbf ; 3 qkv scatter bf16 ;
//      4 raw partial f32 -> C0 + z*M*N
// ---------------------------------------------------------------------------
template<int BM, int EPI>
__global__ __launch_bounds__(256) void mm_bf16_kernel(
        const short* __restrict__ A, const short* __restrict__ BT,
        const float* __restrict__ bias0, const float* __restrict__ bias1,
        const float* __restrict__ bias2, const float* __restrict__ res,
        float* __restrict__ C0, float* __restrict__ C1, float* __restrict__ C2,
        __hip_bfloat16* __restrict__ Cbf, int N, int Kloop, int lda) {
    constexpr int MI = BM / 32;
    __shared__ __align__(16) char As[2][BM * 128];
    __shared__ __align__(16) char Bs[2][128 * 128];
    int nwg = gridDim.x * gridDim.y;
    int bid = blockIdx.y * gridDim.x + blockIdx.x;
    int bx = blockIdx.x, by = blockIdx.y;
    if (!(nwg & 7)) {
        int s = (bid & 7) * (nwg >> 3) + (bid >> 3);
        bx = s % gridDim.x; by = s / gridDim.x;
    }
    int tid = threadIdx.x;
    int lane = tid & 63, wid = tid >> 6;
    int wr = wid >> 1, wc = wid & 1;
    int l15 = lane & 15, l16 = lane >> 4;
    int m0 = bx * BM, n0 = by * 128;
    f32x4 acc[MI][4] = {};

    const size_t lda2 = (size_t)lda * 2;
    const char* Agc = (const char*)A + (size_t)m0 * lda2 + (size_t)blockIdx.z * Kloop * 2;
    const char* Bgc = (const char*)BT + (size_t)n0 * lda2 + (size_t)blockIdx.z * Kloop * 2;

    auto stage = [&](int buf, int kbyte) {
        #pragma unroll
        for (int i = 0; i < BM / 32; ++i) {
            int o = i * 4096 + tid * 16;
            int row = o >> 7, col = o & 127;
            gload16(Agc + (size_t)row * lda2 + kbyte + (col ^ ((row & 7) << 4)),
                    As[buf] + o);
        }
        #pragma unroll
        for (int i = 0; i < 4; ++i) {
            int o = i * 4096 + tid * 16;
            int row = o >> 7, col = o & 127;
            gload16(Bgc + (size_t)row * lda2 + kbyte + (col ^ ((row & 7) << 4)),
                    Bs[buf] + o);
        }
    };
    auto compute = [&](int buf) {
        #pragma unroll
        for (int kk = 0; kk < 2; ++kk) {
            bf16x8 af[MI], bfr[4];
            #pragma unroll
            for (int mi = 0; mi < MI; ++mi) {
                int row = wr * (BM / 2) + mi * 16 + l15;
                af[mi] = *(const bf16x8*)(As[buf] + row * 128 +
                          ((kk * 64 + l16 * 16) ^ ((row & 7) << 4)));
            }
            #pragma unroll
            for (int ni = 0; ni < 4; ++ni) {
                int row = wc * 64 + ni * 16 + l15;
                bfr[ni] = *(const bf16x8*)(Bs[buf] + row * 128 +
                          ((kk * 64 + l16 * 16) ^ ((row & 7) << 4)));
            }
            __builtin_amdgcn_s_setprio(1);
            #pragma unroll
            for (int mi = 0; mi < MI; ++mi)
                #pragma unroll
                for (int ni = 0; ni < 4; ++ni)
                    acc[mi][ni] = __builtin_amdgcn_mfma_f32_16x16x32_bf16(
                        af[mi], bfr[ni], acc[mi][ni], 0, 0, 0);
            __builtin_amdgcn_s_setprio(0);
        }
    };

    const int NT = Kloop / 64;
    stage(0, 0);
    stage(1, 128);
    for (int t = 0; t < NT; ++t) {
        if (t < NT - 1) {
            if constexpr (BM == 128) asm volatile("s_waitcnt vmcnt(8)" ::: "memory");
            else                     asm volatile("s_waitcnt vmcnt(6)" ::: "memory");
        } else {
            asm volatile("s_waitcnt vmcnt(0)" ::: "memory");
        }
        __builtin_amdgcn_sched_barrier(0);
        __builtin_amdgcn_s_barrier();
        __builtin_amdgcn_sched_barrier(0);
        compute(t & 1);
        __builtin_amdgcn_s_barrier();
        __builtin_amdgcn_sched_barrier(0);
        if (t + 2 < NT) stage(t & 1, (t + 2) * 128);
    }

    int rbase = m0 + wr * (BM / 2) + l16 * 4;
    int cbase = n0 + wc * 64 + l15;
    size_t zoff = (EPI == 4) ? (size_t)blockIdx.z * M * N : 0;
    #pragma unroll
    for (int mi = 0; mi < MI; ++mi) {
        #pragma unroll
        for (int ni = 0; ni < 4; ++ni) {
            int col = cbase + ni * 16;
            float bv = 0.f;
            if (EPI == 3) {
                int z = col >> 10, nn = col & 1023;
                bv = (z == 0 ? bias0 : z == 1 ? bias1 : bias2)[nn];
            } else if (EPI != 4) bv = bias0[col];
            #pragma unroll
            for (int r = 0; r < 4; ++r) {
                int row = rbase + mi * 16 + r;
                float v = acc[mi][ni][r] + bv;
                if (EPI == 0) {
                    C0[(size_t)row * N + col] = v;
                } else if (EPI == 1) {
                    C0[(size_t)row * N + col] = v + res[(size_t)row * N + col];
                } else if (EPI == 2) {
                    v = v > 0.f ? v : 0.01f * v;
                    Cbf[(size_t)row * N + col] = __float2bfloat16(v);
                } else if (EPI == 4) {
                    C0[zoff + (size_t)row * N + col] = v;
                } else {
                    int z = col >> 10;
                    int hh = (col >> 6) & 15, e = col & 63;
                    int b = row >> 10, t2 = row & (T - 1);
                    __hip_bfloat16* dst = (__hip_bfloat16*)(z == 0 ? C0 : (z == 1 ? C1 : C2));
                    dst[(((size_t)(b * H + hh)) * T + t2) * HS + e] = __float2bfloat16(v);
                }
            }
        }
    }
}

// ---------------------------------------------------------------------------
// MFMA flash attention, bf16, KVBLK=128, double-buffered K/V staging with
// counted vmcnt. 80 KB LDS -> 2 blocks/CU. grid (T/64, B*H), 4 waves.
// ---------------------------------------------------------------------------
template<int CAUSAL>
__global__ __launch_bounds__(256) void attn_mfma_kernel(
        const short* __restrict__ q, const short* __restrict__ k,
        const short* __restrict__ vt, __hip_bfloat16* __restrict__ att) {
    __shared__ __align__(16) short Ks[2][128 * 64];
    __shared__ __align__(16) short Vs[2][64 * 128];
    __shared__ __align__(16) short Ps[4][16 * 128];
    int bh = blockIdx.y;
    int bI = bh >> 4, h = bh & 15;
    int tix = blockIdx.x;
    if (CAUSAL) tix = (tix & 1) ? (15 - (tix >> 1)) : (tix >> 1);
    int t0 = tix * 64;
    int tid = threadIdx.x;
    int lane = tid & 63, w = tid >> 6;
    int l15 = lane & 15, l16 = lane >> 4;

    const short* Qg = q + ((size_t)bh * T + t0 + w * 16 + l15) * HS + l16 * 8;
    bf16x8 qf0 = *(const bf16x8*)Qg;
    bf16x8 qf1 = *(const bf16x8*)(Qg + 32);

    const char* Kg = (const char*)(k + (size_t)bh * T * HS);
    const char* Vg = (const char*)(vt + (size_t)bh * HS * T);

    float m_run[4] = {-1e30f, -1e30f, -1e30f, -1e30f};
    float l_run[4] = {0.f, 0.f, 0.f, 0.f};
    f32x4 acc_o[4] = {};
    char* Pw = (char*)Ps[w];
    int pswz = l15 << 4;

    auto stageKV = [&](int buf, int s0) {
        #pragma unroll
        for (int i = 0; i < 4; ++i) {
            int o = i * 4096 + tid * 16;
            int row = o >> 7, bir = o & 127;
            gload16(Kg + (size_t)(s0 + row) * 128 + (bir ^ ((row & 7) << 4)),
                    (char*)Ks[buf] + o);
        }
        #pragma unroll
        for (int i = 0; i < 4; ++i) {
            int o = i * 4096 + tid * 16;
            int row = o >> 8, bb = o & 255;
            gload16(Vg + (size_t)row * 2048 + s0 * 2 + (bb ^ ((row & 15) << 4)),
                    (char*)Vs[buf] + o);
        }
    };

    int n_tiles = CAUSAL ? (t0 / 128 + 1) : (T / 128);
    stageKV(0, 0);
    for (int it = 0; it < n_tiles; ++it) {
        int buf = it & 1;
        int s0 = it * 128;
        if (it + 1 < n_tiles) {
            stageKV(buf ^ 1, (it + 1) * 128);
            asm volatile("s_waitcnt vmcnt(8)" ::: "memory");
        } else {
            asm volatile("s_waitcnt vmcnt(0)" ::: "memory");
        }
        __builtin_amdgcn_sched_barrier(0);
        __builtin_amdgcn_s_barrier();
        __builtin_amdgcn_sched_barrier(0);

        f32x4 acc_s[8] = {};
        __builtin_amdgcn_s_setprio(1);
        #pragma unroll
        for (int c = 0; c < 8; ++c) {
            int row = c * 16 + l15;
            const char* kb_ = (const char*)Ks[buf] + row * 128;
            int swz = (row & 7) << 4;
            bf16x8 kf0 = *(const bf16x8*)(kb_ + ((l16 * 16) ^ swz));
            bf16x8 kf1 = *(const bf16x8*)(kb_ + ((64 + l16 * 16) ^ swz));
            acc_s[c] = __builtin_amdgcn_mfma_f32_16x16x32_bf16(qf0, kf0, acc_s[c], 0, 0, 0);
            acc_s[c] = __builtin_amdgcn_mfma_f32_16x16x32_bf16(qf1, kf1, acc_s[c], 0, 0, 0);
        }
        __builtin_amdgcn_s_setprio(0);

        bool domask = CAUSAL && (it == n_tiles - 1);
        #pragma unroll
        for (int r = 0; r < 4; ++r) {
            float sc[8];
            #pragma unroll
            for (int c = 0; c < 8; ++c) {
                float s = acc_s[c][r];
                if (domask && (s0 + c * 16 + l15) > (t0 + w * 16 + l16 * 4 + r)) s = -1e30f;
                sc[c] = s;
            }
            float tm = fmaxf(fmaxf(fmaxf(sc[0], sc[1]), fmaxf(sc[2], sc[3])),
                             fmaxf(fmaxf(sc[4], sc[5]), fmaxf(sc[6], sc[7])));
            tm = fmaxf(tm, __shfl_xor(tm, 1, 16));
            tm = fmaxf(tm, __shfl_xor(tm, 2, 16));
            tm = fmaxf(tm, __shfl_xor(tm, 4, 16));
            tm = fmaxf(tm, __shfl_xor(tm, 8, 16));
            float mn = fmaxf(m_run[r], tm);
            int prow = l16 * 4 + r;
            int pswzr = prow << 4;
            float ls = 0.f;
            #pragma unroll
            for (int c = 0; c < 8; ++c) {
                float pv = __expf(0.125f * (sc[c] - mn));
                int pbyte = prow * 256 + (((c * 16 + l15) * 2) ^ pswzr);
                *(__hip_bfloat16*)(Pw + pbyte) = __float2bfloat16(pv);
                ls += pv;
            }
            ls += __shfl_xor(ls, 1, 16);
            ls += __shfl_xor(ls, 2, 16);
            ls += __shfl_xor(ls, 4, 16);
            ls += __shfl_xor(ls, 8, 16);
            float alpha = __expf(0.125f * (m_run[r] - mn));
            l_run[r] = l_run[r] * alpha + ls;
            m_run[r] = mn;
            acc_o[0][r] *= alpha; acc_o[1][r] *= alpha;
            acc_o[2][r] *= alpha; acc_o[3][r] *= alpha;
        }

        const char* Pb = Pw + l15 * 256;
        bf16x8 pa[4];
        #pragma unroll
        for (int tt = 0; tt < 4; ++tt)
            pa[tt] = *(const bf16x8*)(Pb + ((tt * 64 + l16 * 16) ^ pswz));
        __builtin_amdgcn_s_setprio(1);
        #pragma unroll
        for (int ni = 0; ni < 4; ++ni) {
            int row = ni * 16 + l15;
            const char* vb_ = (const char*)Vs[buf] + row * 256;
            int swz = (row & 15) << 4;
            #pragma unroll
            for (int tt = 0; tt < 4; ++tt) {
                bf16x8 vf = *(const bf16x8*)(vb_ + ((tt * 64 + l16 * 16) ^ swz));
                acc_o[ni] = __builtin_amdgcn_mfma_f32_16x16x32_bf16(pa[tt], vf, acc_o[ni], 0, 0, 0);
            }
        }
        __builtin_amdgcn_s_setprio(0);
        __builtin_amdgcn_s_barrier();
        __builtin_amdgcn_sched_barrier(0);
    }

    float inv[4];
    #pragma unroll
    for (int r = 0; r < 4; ++r) inv[r] = 1.0f / l_run[r];
    #pragma unroll
    for (int ni = 0; ni < 4; ++ni) {
        #pragma unroll
        for (int r = 0; r < 4; ++r) {
            size_t orow = ((size_t)(bI * T) + t0 + w * 16 + l16 * 4 + r) * D
                        + h * HS + ni * 16 + l15;
            att[orow] = __float2bfloat16(acc_o[ni][r] * inv[r]);
        }
    }
}

// ---------------------------------------------------------------------------
extern "C" void kernel_launch(void* const* d_in, const int* in_sizes, int n_in,
                              void* d_out, int out_size, void* d_ws, size_t ws_size,
                              hipStream_t stream) {
    const int*   idx     = (const int*)d_in[0];
    const float* tok_emb = (const float*)d_in[1];
    const float* pos_emb = (const float*)d_in[2];
    const float* Wq_u = (const float*)d_in[3],  *bq_u = (const float*)d_in[4];
    const float* Wk_u = (const float*)d_in[5],  *bk_u = (const float*)d_in[6];
    const float* Wv_u = (const float*)d_in[7],  *bv_u = (const float*)d_in[8];
    const float* Wp_u = (const float*)d_in[9],  *bp_u = (const float*)d_in[10];
    const float* Wq_m = (const float*)d_in[11], *bq_m = (const float*)d_in[12];
    const float* Wk_m = (const float*)d_in[13], *bk_m = (const float*)d_in[14];
    const float* Wv_m = (const float*)d_in[15], *bv_m = (const float*)d_in[16];
    const float* Wp_m = (const float*)d_in[17], *bp_m = (const float*)d_in[18];
    const float* W1   = (const float*)d_in[19], *b1   = (const float*)d_in[20];
    const float* W2   = (const float*)d_in[21], *b2   = (const float*)d_in[22];
    const float* lnf_g = (const float*)d_in[23], *lnf_b = (const float*)d_in[24];
    const float* n1_g  = (const float*)d_in[25], *n1_b  = (const float*)d_in[26];
    const float* n2_g  = (const float*)d_in[27], *n2_b  = (const float*)d_in[28];
    const float* nf_g  = (const float*)d_in[29], *nf_b  = (const float*)d_in[30];
    const float* Wfin  = (const float*)d_in[31], *bfin  = (const float*)d_in[32];
    float* out = (float*)d_out;

    char* p = (char*)d_ws;
    auto alloc = [&](size_t bytes) { char* r = p; p += (bytes + 255) & ~255ull; return r; };
    float* x    = (float*)alloc((size_t)M * D * 4);
    float* x2   = (float*)alloc((size_t)M * D * 4);
    float* w2p  = (float*)alloc((size_t)4 * M * D * 4);
    short* qbf  = (short*)alloc((size_t)M * D * 2);
    short* kbf  = (short*)alloc((size_t)M * D * 2);
    short* vbf  = (short*)alloc((size_t)M * D * 2);
    short* vtb  = (short*)alloc((size_t)M * D * 2);
    short* xnb  = (short*)alloc((size_t)M * D * 2);
    short* attb = (short*)alloc((size_t)M * D * 2);
    short* hb   = (short*)alloc((size_t)M * DFF * 2);
    short* WqkvT= (short*)alloc((size_t)2 * 3 * H * HS * D * 2);
    short* WpT  = (short*)alloc((size_t)2 * D * D * 2);
    short* W1T  = (short*)alloc((size_t)D * DFF * 2);
    short* W2T  = (short*)alloc((size_t)DFF * D * 2);
    short* WfT  = (short*)alloc((size_t)D * V * 2);

    embed_ln_kernel<<<M / 4, 256, 0, stream>>>(idx, tok_emb, pos_emb,
        n1_g, n1_b, x, (__hip_bfloat16*)xnb);
    transpose_bf16_kernel<<<dim3(V / 32, D / 32), 256, 0, stream>>>(
        Wfin, (__hip_bfloat16*)WfT, D, V);

    for (int l = 0; l < LNUM; ++l) {
        const float *n1g = n1_g + l * D, *n1b = n1_b + l * D;
        const float *n2g = n2_g + l * D, *n2b = n2_b + l * D;
        const float *lfg = lnf_g + l * D, *lfb = lnf_b + l * D;
        const float *W1l = W1 + (size_t)l * D * DFF, *b1l = b1 + l * DFF;
        const float *W2l = W2 + (size_t)l * DFF * D, *b2l = b2 + l * D;
        trans_w12_kernel<<<dim3(160, 32, 2), 256, 0, stream>>>(
            W1l, W2l, W1T, W2T);
        trans_qkvp2_kernel<<<dim3(32, 32, 8), 256, 0, stream>>>(
            Wq_u + (size_t)l * H * D * HS, Wk_u + (size_t)l * H * D * HS,
            Wv_u + (size_t)l * H * D * HS, Wp_u + (size_t)l * D * D,
            Wq_m + (size_t)l * H * D * HS, Wk_m + (size_t)l * H * D * HS,
            Wv_m + (size_t)l * H * D * HS, Wp_m + (size_t)l * D * D,
            WqkvT, WpT);
        for (int half = 0; half < 2; ++half) {
            const float *bq_, *bk_, *bv_, *bp_;
            if (half == 0) { bq_ = bq_u; bk_ = bk_u; bv_ = bv_u; bp_ = bp_u; }
            else           { bq_ = bq_m; bk_ = bk_m; bv_ = bv_m; bp_ = bp_m; }
            bq_ += l * H * HS;  bk_ += l * H * HS;  bv_ += l * H * HS;  bp_ += l * D;
            const short* WqkvTh = WqkvT + (size_t)half * 3 * H * HS * D;
            const short* WpTh   = WpT + (size_t)half * D * D;

            // q,k,v = xn @ Wqkv -> bf16 [B,H,T,HS]
            mm_bf16_kernel<128, 3><<<dim3(M / 128, 3072 / 128), 256, 0, stream>>>(
                xnb, WqkvTh, bq_, bk_, bv_, nullptr,
                (float*)qbf, (float*)kbf, (float*)vbf, nullptr, 3072, D, D);
            transpose_v_kernel<<<dim3(HS / 32, T / 32, BB * H), 256, 0, stream>>>(vbf, vtb);
            if (half == 0)
                attn_mfma_kernel<0><<<dim3(T / 64, BB * H), 256, 0, stream>>>(
                    qbf, kbf, vtb, (__hip_bfloat16*)attb);
            else
                attn_mfma_kernel<1><<<dim3(T / 64, BB * H), 256, 0, stream>>>(
                    qbf, kbf, vtb, (__hip_bfloat16*)attb);
            // att @ Wp  split-K x2 -> partials (512 blocks)
            mm_bf16_kernel<64, 4><<<dim3(M / 64, D / 128, 2), 256, 0, stream>>>(
                attb, WpTh, nullptr, nullptr, nullptr, nullptr, w2p, nullptr, nullptr,
                nullptr, D, D / 2, D);
            // proj tail: x2 = x + p0 + p1 + bp ; xn = ln(x2, n2)
            proj_tail_kernel<<<M / 4, 256, 0, stream>>>(
                w2p, bp_, x, n2g, n2b, x2, (__hip_bfloat16*)xnb);
            // h = leaky(xn @ W1 + b1) -> bf16  (128-tile, 640 blocks = full fill)
            mm_bf16_kernel<128, 2><<<dim3(M / 128, DFF / 128), 256, 0, stream>>>(
                xnb, W1T, b1l, nullptr, nullptr, nullptr, nullptr, nullptr, nullptr,
                (__hip_bfloat16*)hb, DFF, D, D);
            // W2 split-K x4 -> partials (512 blocks, 2/CU)
            mm_bf16_kernel<128, 4><<<dim3(M / 128, D / 128, 4), 256, 0, stream>>>(
                hb, W2T, nullptr, nullptr, nullptr, nullptr, w2p, nullptr, nullptr,
                nullptr, D, DFF / 4, DFF);
            const float* og = half ? n2g : n1g;
            const float* ob = half ? n2b : n1b;
            const float* gn; const float* bn;
            if (half == 0)      { gn = n1g; bn = n1b; }
            else if (l < LNUM-1){ gn = n1_g + (l+1)*D; bn = n1_b + (l+1)*D; }
            else                { gn = nf_g; bn = nf_b; }
            ffn_tail_kernel<4><<<M / 4, 256, 0, stream>>>(
                w2p, b2l, lfg, lfb, og, ob, x2, x, gn, bn, (__hip_bfloat16*)xnb);
        }
    }
    // vocab head
    mm256_kernel<0><<<(M / 256) * (V / 256), 512, 0, stream>>>(
        xnb, WfT, bfin, out, nullptr, V, D, D);
}

// Round 18
// 1499.581 us; speedup vs baseline: 1.0385x; 1.0385x over previous
//
#include <hip/hip_runtime.h>
#include <hip/hip_bf16.h>
#include <math.h>

#define LNUM 4
#define H 16
#define D 1024
#define HS 64
#define DFF 5120
#define V 32000
#define BB 2
#define T 1024
#define M (BB*T)          // 2048 token rows
#define EPS 1e-5f

typedef __attribute__((ext_vector_type(8))) short bf16x8;
typedef __attribute__((ext_vector_type(4))) float f32x4;

// async global->LDS, 16B per lane (wave-uniform LDS base + lane*16)
__device__ __forceinline__ void gload16(const void* g, void* l) {
    __builtin_amdgcn_global_load_lds(
        (const __attribute__((address_space(1))) void*)g,
        (__attribute__((address_space(3))) void*)l, 16, 0, 0);
}

__device__ __forceinline__ float wred_sum(float v) {
    #pragma unroll
    for (int off = 32; off; off >>= 1) v += __shfl_xor(v, off, 64);
    return v;
}

// ---------------------------------------------------------------------------
// embed + first pre-attn LN fused (wave-per-row, 4 rows/block)
// ---------------------------------------------------------------------------
__global__ __launch_bounds__(256) void embed_ln_kernel(const int* __restrict__ idx,
        const float* __restrict__ tok, const float* __restrict__ pos,
        const float* __restrict__ g, const float* __restrict__ b,
        float* __restrict__ x, __hip_bfloat16* __restrict__ xn) {
    int w = threadIdx.x >> 6, lane = threadIdx.x & 63;
    int row = blockIdx.x * 4 + w;
    int t = row & (T - 1);
    int tok_id = idx[row];
    const float* tp = tok + (size_t)tok_id * D;
    const float* pp = pos + (size_t)t * D;
    float4 xv[4];
    float s = 0.f;
    #pragma unroll
    for (int c = 0; c < 4; ++c) {
        int j = c * 256 + lane * 4;
        float4 a = *(const float4*)&tp[j];
        float4 p = *(const float4*)&pp[j];
        a.x += p.x; a.y += p.y; a.z += p.z; a.w += p.w;
        *(float4*)&x[(size_t)row * D + j] = a;
        xv[c] = a;
        s += a.x + a.y + a.z + a.w;
    }
    float mu = wred_sum(s) * (1.0f / D);
    float vs = 0.f;
    #pragma unroll
    for (int c = 0; c < 4; ++c) {
        xv[c].x -= mu; xv[c].y -= mu; xv[c].z -= mu; xv[c].w -= mu;
        vs += xv[c].x*xv[c].x + xv[c].y*xv[c].y + xv[c].z*xv[c].z + xv[c].w*xv[c].w;
    }
    float rs = rsqrtf(wred_sum(vs) * (1.0f / D) + EPS);
    #pragma unroll
    for (int c = 0; c < 4; ++c) {
        int j = c * 256 + lane * 4;
        float4 gv = *(const float4*)&g[j];
        float4 bv = *(const float4*)&b[j];
        union { ushort4 u4; __hip_bfloat16 h[4]; } pk;
        pk.h[0] = __float2bfloat16(xv[c].x * rs * gv.x + bv.x);
        pk.h[1] = __float2bfloat16(xv[c].y * rs * gv.y + bv.y);
        pk.h[2] = __float2bfloat16(xv[c].z * rs * gv.z + bv.z);
        pk.h[3] = __float2bfloat16(xv[c].w * rs * gv.w + bv.w);
        *(ushort4*)&xn[(size_t)row * D + j] = pk.u4;
    }
}

// ---------------------------------------------------------------------------
// proj tail, fused: x2 = x + p0 + p1 + bp ; xn = ln(x2, n2) -> bf16
// ---------------------------------------------------------------------------
__global__ __launch_bounds__(256) void proj_tail_kernel(
        const float* __restrict__ part, const float* __restrict__ bp,
        const float* __restrict__ res,
        const float* __restrict__ g, const float* __restrict__ b,
        float* __restrict__ x2out, __hip_bfloat16* __restrict__ xnout) {
    const size_t MD = (size_t)M * D;
    int w = threadIdx.x >> 6, lane = threadIdx.x & 63;
    int row = blockIdx.x * 4 + w;
    size_t ro = (size_t)row * D;
    float4 f[4];
    float s = 0.f;
    #pragma unroll
    for (int c = 0; c < 4; ++c) {
        int j = c * 256 + lane * 4;
        float4 rv = *(const float4*)&res[ro + j];
        float4 p0 = *(const float4*)&part[ro + j];
        float4 p1 = *(const float4*)&part[MD + ro + j];
        float4 bv = *(const float4*)&bp[j];
        float4 a;
        a.x = rv.x + p0.x + p1.x + bv.x;
        a.y = rv.y + p0.y + p1.y + bv.y;
        a.z = rv.z + p0.z + p1.z + bv.z;
        a.w = rv.w + p0.w + p1.w + bv.w;
        *(float4*)&x2out[ro + j] = a;
        f[c] = a;
        s += a.x + a.y + a.z + a.w;
    }
    float mu = wred_sum(s) * (1.0f / D);
    float vs = 0.f;
    #pragma unroll
    for (int c = 0; c < 4; ++c) {
        f[c].x -= mu; f[c].y -= mu; f[c].z -= mu; f[c].w -= mu;
        vs += f[c].x*f[c].x + f[c].y*f[c].y + f[c].z*f[c].z + f[c].w*f[c].w;
    }
    float rs = rsqrtf(wred_sum(vs) * (1.0f / D) + EPS);
    #pragma unroll
    for (int c = 0; c < 4; ++c) {
        int j = c * 256 + lane * 4;
        float4 gv = *(const float4*)&g[j];
        float4 bv = *(const float4*)&b[j];
        union { ushort4 u4; __hip_bfloat16 h[4]; } pk;
        pk.h[0] = __float2bfloat16(f[c].x * rs * gv.x + bv.x);
        pk.h[1] = __float2bfloat16(f[c].y * rs * gv.y + bv.y);
        pk.h[2] = __float2bfloat16(f[c].z * rs * gv.z + bv.z);
        pk.h[3] = __float2bfloat16(f[c].w * rs * gv.w + bv.w);
        *(ushort4*)&xnout[ro + j] = pk.u4;
    }
}

// ---------------------------------------------------------------------------
// FFN tail, fused:  f = sum(partials)+b2 ; x = res + ln(ln(f,g1,b1),g2,b2g)
// then xn = ln(x, gn, bn) -> bf16
// ---------------------------------------------------------------------------
template<int NP>
__global__ __launch_bounds__(256) void ffn_tail_kernel(
        const float* __restrict__ part, const float* __restrict__ b2,
        const float* __restrict__ g1, const float* __restrict__ b1,
        const float* __restrict__ g2, const float* __restrict__ b2g,
        const float* __restrict__ res, float* __restrict__ xout,
        const float* __restrict__ gn, const float* __restrict__ bn,
        __hip_bfloat16* __restrict__ xnout) {
    const size_t MD = (size_t)M * D;
    int w = threadIdx.x >> 6, lane = threadIdx.x & 63;
    int row = blockIdx.x * 4 + w;
    size_t ro = (size_t)row * D;
    float4 f[4];
    float s = 0.f;
    #pragma unroll
    for (int c = 0; c < 4; ++c) {
        int j = c * 256 + lane * 4;
        float4 acc = *(const float4*)&b2[j];
        #pragma unroll
        for (int pI = 0; pI < NP; ++pI) {
            float4 pv = *(const float4*)&part[pI * MD + ro + j];
            acc.x += pv.x; acc.y += pv.y; acc.z += pv.z; acc.w += pv.w;
        }
        f[c] = acc;
        s += acc.x + acc.y + acc.z + acc.w;
    }
    float mu = wred_sum(s) * (1.0f / D);
    float vs = 0.f;
    #pragma unroll
    for (int c = 0; c < 4; ++c) {
        f[c].x -= mu; f[c].y -= mu; f[c].z -= mu; f[c].w -= mu;
        vs += f[c].x*f[c].x + f[c].y*f[c].y + f[c].z*f[c].z + f[c].w*f[c].w;
    }
    float rs = rsqrtf(wred_sum(vs) * (1.0f / D) + EPS);
    float s2 = 0.f;
    #pragma unroll
    for (int c = 0; c < 4; ++c) {
        int j = c * 256 + lane * 4;
        float4 gv = *(const float4*)&g1[j];
        float4 bv = *(const float4*)&b1[j];
        f[c].x = f[c].x * rs * gv.x + bv.x;
        f[c].y = f[c].y * rs * gv.y + bv.y;
        f[c].z = f[c].z * rs * gv.z + bv.z;
        f[c].w = f[c].w * rs * gv.w + bv.w;
        s2 += f[c].x + f[c].y + f[c].z + f[c].w;
    }
    float mu2 = wred_sum(s2) * (1.0f / D);
    float vs2 = 0.f;
    #pragma unroll
    for (int c = 0; c < 4; ++c) {
        f[c].x -= mu2; f[c].y -= mu2; f[c].z -= mu2; f[c].w -= mu2;
        vs2 += f[c].x*f[c].x + f[c].y*f[c].y + f[c].z*f[c].z + f[c].w*f[c].w;
    }
    float rs2 = rsqrtf(wred_sum(vs2) * (1.0f / D) + EPS);
    float s3 = 0.f;
    #pragma unroll
    for (int c = 0; c < 4; ++c) {
        int j = c * 256 + lane * 4;
        float4 gv = *(const float4*)&g2[j];
        float4 bv = *(const float4*)&b2g[j];
        float4 rv = *(const float4*)&res[ro + j];
        f[c].x = rv.x + f[c].x * rs2 * gv.x + bv.x;
        f[c].y = rv.y + f[c].y * rs2 * gv.y + bv.y;
        f[c].z = rv.z + f[c].z * rs2 * gv.z + bv.z;
        f[c].w = rv.w + f[c].w * rs2 * gv.w + bv.w;
        *(float4*)&xout[ro + j] = f[c];
        s3 += f[c].x + f[c].y + f[c].z + f[c].w;
    }
    float mu3 = wred_sum(s3) * (1.0f / D);
    float vs3 = 0.f;
    #pragma unroll
    for (int c = 0; c < 4; ++c) {
        f[c].x -= mu3; f[c].y -= mu3; f[c].z -= mu3; f[c].w -= mu3;
        vs3 += f[c].x*f[c].x + f[c].y*f[c].y + f[c].z*f[c].z + f[c].w*f[c].w;
    }
    float rs3 = rsqrtf(wred_sum(vs3) * (1.0f / D) + EPS);
    #pragma unroll
    for (int c = 0; c < 4; ++c) {
        int j = c * 256 + lane * 4;
        float4 gv = *(const float4*)&gn[j];
        float4 bv = *(const float4*)&bn[j];
        union { ushort4 u4; __hip_bfloat16 h[4]; } pk;
        pk.h[0] = __float2bfloat16(f[c].x * rs3 * gv.x + bv.x);
        pk.h[1] = __float2bfloat16(f[c].y * rs3 * gv.y + bv.y);
        pk.h[2] = __float2bfloat16(f[c].z * rs3 * gv.z + bv.z);
        pk.h[3] = __float2bfloat16(f[c].w * rs3 * gv.w + bv.w);
        *(ushort4*)&xnout[ro + j] = pk.u4;
    }
}

// ---------------------------------------------------------------------------
// tiled transpose + fp32->bf16: in [R][C] f32 -> out [C][R] bf16 (Wfin)
// ---------------------------------------------------------------------------
__global__ __launch_bounds__(256) void transpose_bf16_kernel(
        const float* __restrict__ in, __hip_bfloat16* __restrict__ out,
        int R, int C) {
    __shared__ float t[32][33];
    int tx = threadIdx.x & 31, ty = threadIdx.x >> 5;
    int c0 = blockIdx.x * 32, r0 = blockIdx.y * 32;
    #pragma unroll
    for (int i = 0; i < 4; ++i)
        t[ty + i * 8][tx] = in[(size_t)(r0 + ty + i * 8) * C + c0 + tx];
    __syncthreads();
    #pragma unroll
    for (int i = 0; i < 4; ++i)
        out[(size_t)(c0 + ty + i * 8) * R + r0 + tx] = __float2bfloat16(t[tx][ty + i * 8]);
}

// ---------------------------------------------------------------------------
// per-LAYER weight prep (both halves) in ONE launch: grid (32, 32, 8)
// ---------------------------------------------------------------------------
__global__ __launch_bounds__(256) void trans_qkvp2_kernel(
        const float* __restrict__ Wq0, const float* __restrict__ Wk0,
        const float* __restrict__ Wv0, const float* __restrict__ Wp0,
        const float* __restrict__ Wq1, const float* __restrict__ Wk1,
        const float* __restrict__ Wv1, const float* __restrict__ Wp1,
        short* __restrict__ qkvT, short* __restrict__ WpT) {
    __shared__ float t[32][33];
    int tx = threadIdx.x & 31, ty = threadIdx.x >> 5;
    int z = blockIdx.z;
    int half = z >> 2, which = z & 3;
    const float* in;
    __hip_bfloat16* out;
    int inC, outC, c0;
    int r0 = blockIdx.y * 32;
    if (which < 3) {
        int c0g = blockIdx.x * 32;
        int h = c0g >> 6;
        c0 = c0g & 63;
        const float* base = which == 0 ? (half ? Wq1 : Wq0)
                          : which == 1 ? (half ? Wk1 : Wk0)
                                       : (half ? Wv1 : Wv0);
        in = base + (size_t)h * D * HS;
        out = (__hip_bfloat16*)qkvT + (size_t)half * 3 * H * HS * D
            + ((size_t)which * H + h) * HS * D;
        inC = HS; outC = D;
    } else {
        c0 = blockIdx.x * 32;
        in = half ? Wp1 : Wp0;
        out = (__hip_bfloat16*)WpT + (size_t)half * D * D;
        inC = D; outC = D;
    }
    #pragma unroll
    for (int i = 0; i < 4; ++i)
        t[ty + i * 8][tx] = in[(size_t)(r0 + ty + i * 8) * inC + c0 + tx];
    __syncthreads();
    #pragma unroll
    for (int i = 0; i < 4; ++i)
        out[(size_t)(c0 + ty + i * 8) * outC + r0 + tx] = __float2bfloat16(t[tx][ty + i * 8]);
}

// ---------------------------------------------------------------------------
// per-layer W1+W2 transpose in ONE launch: grid (160, 32, 2)
// ---------------------------------------------------------------------------
__global__ __launch_bounds__(256) void trans_w12_kernel(
        const float* __restrict__ W1, const float* __restrict__ W2,
        short* __restrict__ W1T, short* __restrict__ W2T) {
    __shared__ float t[32][33];
    int tx = threadIdx.x & 31, ty = threadIdx.x >> 5;
    int z = blockIdx.z;
    const float* in; __hip_bfloat16* out;
    int inC, outC, r0, c0;
    if (z == 0) { in = W1; out = (__hip_bfloat16*)W1T; inC = DFF; outC = D;
                  r0 = blockIdx.y * 32; c0 = blockIdx.x * 32; }
    else        { in = W2; out = (__hip_bfloat16*)W2T; inC = D; outC = DFF;
                  r0 = blockIdx.x * 32; c0 = blockIdx.y * 32; }
    #pragma unroll
    for (int i = 0; i < 4; ++i)
        t[ty + i * 8][tx] = in[(size_t)(r0 + ty + i * 8) * inC + c0 + tx];
    __syncthreads();
    #pragma unroll
    for (int i = 0; i < 4; ++i)
        out[(size_t)(c0 + ty + i * 8) * outC + r0 + tx] = __float2bfloat16(t[tx][ty + i * 8]);
}

// ---------------------------------------------------------------------------
// bf16->bf16 transpose for V: in [T][HS] per bh -> out [HS][T]
// ---------------------------------------------------------------------------
__global__ __launch_bounds__(256) void transpose_v_kernel(const short* __restrict__ in,
        short* __restrict__ out) {
    __shared__ short t[32][33];
    int z = blockIdx.z;
    in  += (size_t)z * T * HS;
    out += (size_t)z * HS * T;
    int tx = threadIdx.x & 31, ty = threadIdx.x >> 5;
    int c0 = blockIdx.x * 32, r0 = blockIdx.y * 32;
    #pragma unroll
    for (int i = 0; i < 4; ++i)
        t[ty + i * 8][tx] = in[(size_t)(r0 + ty + i * 8) * HS + c0 + tx];
    __syncthreads();
    #pragma unroll
    for (int i = 0; i < 4; ++i)
        out[(size_t)(c0 + ty + i * 8) * T + r0 + tx] = t[tx][ty + i * 8];
}

// ---------------------------------------------------------------------------
// 256x256 bf16 MFMA GEMM, 2 phases per K-tile (BK=64). 512 thr = 8 waves.
// EPI: 0 f32+bias -> C0 ; 2 leaky -> bf16 Cbf.  M fixed = 2048 (8 M-tiles).
// ---------------------------------------------------------------------------
template<int EPI>
__global__ __launch_bounds__(512, 2) void mm256_kernel(
        const short* __restrict__ A, const short* __restrict__ BT,
        const float* __restrict__ bias0, float* __restrict__ C0,
        __hip_bfloat16* __restrict__ Cbf, int N, int Kloop, int lda) {
    __shared__ __align__(16) char LA[2][2][256 * 64];
    __shared__ __align__(16) char LB[2][2][256 * 64];
    int tid = threadIdx.x;
    int lane = tid & 63, wid = tid >> 6;
    int wr = wid >> 2, wc = wid & 3;
    int l15 = lane & 15, l16 = lane >> 4;

    int nwg = gridDim.x;
    int bid = blockIdx.x;
    int q = nwg >> 3, r = nwg & 7;
    int xcd = bid & 7, loc = bid >> 3;
    int wg = (xcd < r ? xcd * (q + 1) : r * (q + 1) + (xcd - r) * q) + loc;
    int m0 = (wg & 7) * 256;
    int n0 = (wg >> 3) * 256;

    const size_t lda2 = (size_t)lda * 2;
    const char* Agc = (const char*)A + (size_t)m0 * lda2;
    const char* Bgc = (const char*)BT + (size_t)n0 * lda2;

    f32x4 acc[8][4] = {};
    bf16x8 af[8], bfr[4];

    auto stA = [&](int buf, int kh, int kt) {
        #pragma unroll
        for (int i = 0; i < 2; ++i) {
            int o = i * 8192 + tid * 16;
            int row = o >> 6, col = o & 63;
            gload16(Agc + (size_t)row * lda2 + kt * 128 + kh * 64 +
                    (col ^ (((row >> 1) & 3) << 4)), LA[buf][kh] + o);
        }
    };
    auto stB = [&](int buf, int kh, int kt) {
        #pragma unroll
        for (int i = 0; i < 2; ++i) {
            int o = i * 8192 + tid * 16;
            int row = o >> 6, col = o & 63;
            gload16(Bgc + (size_t)row * lda2 + kt * 128 + kh * 64 +
                    (col ^ (((row >> 1) & 3) << 4)), LB[buf][kh] + o);
        }
    };
    auto rdA = [&](int buf, int kk) {
        #pragma unroll
        for (int mf = 0; mf < 8; ++mf) {
            int row = wr * 128 + mf * 16 + l15;
            af[mf] = *(const bf16x8*)(LA[buf][kk] + row * 64 +
                      ((l16 * 16) ^ (((row >> 1) & 3) << 4)));
        }
    };
    auto rdB4 = [&](int buf, int kk) {
        #pragma unroll
        for (int nf = 0; nf < 4; ++nf) {
            int row = wc * 64 + nf * 16 + l15;
            bfr[nf] = *(const bf16x8*)(LB[buf][kk] + row * 64 +
                       ((l16 * 16) ^ (((row >> 1) & 3) << 4)));
        }
    };
    auto mfma32 = [&]() {
        __builtin_amdgcn_s_setprio(1);
        #pragma unroll
        for (int mf = 0; mf < 8; ++mf)
            #pragma unroll
            for (int nf = 0; nf < 4; ++nf)
                acc[mf][nf] = __builtin_amdgcn_mfma_f32_16x16x32_bf16(
                    af[mf], bfr[nf], acc[mf][nf], 0, 0, 0);
        __builtin_amdgcn_s_setprio(0);
    };

    const int NT = Kloop / 64;
    stA(0, 0, 0); stB(0, 0, 0); stA(0, 1, 0); stB(0, 1, 0);
    stA(1, 0, 1); stB(1, 0, 1);
    asm volatile("s_waitcnt vmcnt(4)" ::: "memory");
    __builtin_amdgcn_sched_barrier(0);
    __builtin_amdgcn_s_barrier();
    __builtin_amdgcn_sched_barrier(0);

    for (int t = 0; t < NT; ++t) {
        int buf = t & 1;
        rdA(buf, 0); rdB4(buf, 0);
        if (t + 1 < NT) { stA(buf ^ 1, 1, t + 1); stB(buf ^ 1, 1, t + 1); }
        mfma32();
        __builtin_amdgcn_sched_barrier(0);
        __builtin_amdgcn_s_barrier();
        __builtin_amdgcn_sched_barrier(0);
        rdA(buf, 1); rdB4(buf, 1);
        if (t + 2 < NT) { stA(buf, 0, t + 2); stB(buf, 0, t + 2); }
        mfma32();
        if (t + 2 < NT) { asm volatile("s_waitcnt vmcnt(4)" ::: "memory"); }
        else            { asm volatile("s_waitcnt vmcnt(0)" ::: "memory"); }
        __builtin_amdgcn_sched_barrier(0);
        __builtin_amdgcn_s_barrier();
        __builtin_amdgcn_sched_barrier(0);
    }

    #pragma unroll
    for (int mf = 0; mf < 8; ++mf) {
        #pragma unroll
        for (int nf = 0; nf < 4; ++nf) {
            int col = n0 + wc * 64 + nf * 16 + l15;
            float bv = bias0[col];
            #pragma unroll
            for (int rr = 0; rr < 4; ++rr) {
                int row = m0 + wr * 128 + mf * 16 + l16 * 4 + rr;
                float v = acc[mf][nf][rr] + bv;
                if (EPI == 0) {
                    C0[(size_t)row * N + col] = v;
                } else {
                    v = v > 0.f ? v : 0.01f * v;
                    Cbf[(size_t)row * N + col] = __float2bfloat16(v);
                }
            }
        }
    }
}

// ---------------------------------------------------------------------------
// bf16 MFMA GEMM (128-tile, double-buffered counted-vmcnt) — qkv/proj/W2.
// EPI: 0 f32 C0 ; 1 +res f32 C0 ; 2 leaky bf16 Cbf ; 3 qkv scatter bf16 ;
//      4 raw partial f32 -> C0 + z*M*N
// ---------------------------------------------------------------------------
template<int BM, int EPI>
__global__ __launch_bounds__(256) void mm_bf16_kernel(
        const short* __restrict__ A, const short* __restrict__ BT,
        const float* __restrict__ bias0, const float* __restrict__ bias1,
        const float* __restrict__ bias2, const float* __restrict__ res,
        float* __restrict__ C0, float* __restrict__ C1, float* __restrict__ C2,
        __hip_bfloat16* __restrict__ Cbf, int N, int Kloop, int lda) {
    constexpr int MI = BM / 32;
    __shared__ __align__(16) char As[2][BM * 128];
    __shared__ __align__(16) char Bs[2][128 * 128];
    int nwg = gridDim.x * gridDim.y;
    int bid = blockIdx.y * gridDim.x + blockIdx.x;
    int bx = blockIdx.x, by = blockIdx.y;
    if (!(nwg & 7)) {
        int s = (bid & 7) * (nwg >> 3) + (bid >> 3);
        bx = s % gridDim.x; by = s / gridDim.x;
    }
    int tid = threadIdx.x;
    int lane = tid & 63, wid = tid >> 6;
    int wr = wid >> 1, wc = wid & 1;
    int l15 = lane & 15, l16 = lane >> 4;
    int m0 = bx * BM, n0 = by * 128;
    f32x4 acc[MI][4] = {};

    const size_t lda2 = (size_t)lda * 2;
    const char* Agc = (const char*)A + (size_t)m0 * lda2 + (size_t)blockIdx.z * Kloop * 2;
    const char* Bgc = (const char*)BT + (size_t)n0 * lda2 + (size_t)blockIdx.z * Kloop * 2;

    auto stage = [&](int buf, int kbyte) {
        #pragma unroll
        for (int i = 0; i < BM / 32; ++i) {
            int o = i * 4096 + tid * 16;
            int row = o >> 7, col = o & 127;
            gload16(Agc + (size_t)row * lda2 + kbyte + (col ^ ((row & 7) << 4)),
                    As[buf] + o);
        }
        #pragma unroll
        for (int i = 0; i < 4; ++i) {
            int o = i * 4096 + tid * 16;
            int row = o >> 7, col = o & 127;
            gload16(Bgc + (size_t)row * lda2 + kbyte + (col ^ ((row & 7) << 4)),
                    Bs[buf] + o);
        }
    };
    auto compute = [&](int buf) {
        #pragma unroll
        for (int kk = 0; kk < 2; ++kk) {
            bf16x8 af[MI], bfr[4];
            #pragma unroll
            for (int mi = 0; mi < MI; ++mi) {
                int row = wr * (BM / 2) + mi * 16 + l15;
                af[mi] = *(const bf16x8*)(As[buf] + row * 128 +
                          ((kk * 64 + l16 * 16) ^ ((row & 7) << 4)));
            }
            #pragma unroll
            for (int ni = 0; ni < 4; ++ni) {
                int row = wc * 64 + ni * 16 + l15;
                bfr[ni] = *(const bf16x8*)(Bs[buf] + row * 128 +
                          ((kk * 64 + l16 * 16) ^ ((row & 7) << 4)));
            }
            __builtin_amdgcn_s_setprio(1);
            #pragma unroll
            for (int mi = 0; mi < MI; ++mi)
                #pragma unroll
                for (int ni = 0; ni < 4; ++ni)
                    acc[mi][ni] = __builtin_amdgcn_mfma_f32_16x16x32_bf16(
                        af[mi], bfr[ni], acc[mi][ni], 0, 0, 0);
            __builtin_amdgcn_s_setprio(0);
        }
    };

    const int NT = Kloop / 64;
    stage(0, 0);
    stage(1, 128);
    for (int t = 0; t < NT; ++t) {
        if (t < NT - 1) {
            if constexpr (BM == 128) asm volatile("s_waitcnt vmcnt(8)" ::: "memory");
            else                     asm volatile("s_waitcnt vmcnt(6)" ::: "memory");
        } else {
            asm volatile("s_waitcnt vmcnt(0)" ::: "memory");
        }
        __builtin_amdgcn_sched_barrier(0);
        __builtin_amdgcn_s_barrier();
        __builtin_amdgcn_sched_barrier(0);
        compute(t & 1);
        __builtin_amdgcn_s_barrier();
        __builtin_amdgcn_sched_barrier(0);
        if (t + 2 < NT) stage(t & 1, (t + 2) * 128);
    }

    int rbase = m0 + wr * (BM / 2) + l16 * 4;
    int cbase = n0 + wc * 64 + l15;
    size_t zoff = (EPI == 4) ? (size_t)blockIdx.z * M * N : 0;
    #pragma unroll
    for (int mi = 0; mi < MI; ++mi) {
        #pragma unroll
        for (int ni = 0; ni < 4; ++ni) {
            int col = cbase + ni * 16;
            float bv = 0.f;
            if (EPI == 3) {
                int z = col >> 10, nn = col & 1023;
                bv = (z == 0 ? bias0 : z == 1 ? bias1 : bias2)[nn];
            } else if (EPI != 4) bv = bias0[col];
            #pragma unroll
            for (int r = 0; r < 4; ++r) {
                int row = rbase + mi * 16 + r;
                float v = acc[mi][ni][r] + bv;
                if (EPI == 0) {
                    C0[(size_t)row * N + col] = v;
                } else if (EPI == 1) {
                    C0[(size_t)row * N + col] = v + res[(size_t)row * N + col];
                } else if (EPI == 2) {
                    v = v > 0.f ? v : 0.01f * v;
                    Cbf[(size_t)row * N + col] = __float2bfloat16(v);
                } else if (EPI == 4) {
                    C0[zoff + (size_t)row * N + col] = v;
                } else {
                    int z = col >> 10;
                    int hh = (col >> 6) & 15, e = col & 63;
                    int b = row >> 10, t2 = row & (T - 1);
                    __hip_bfloat16* dst = (__hip_bfloat16*)(z == 0 ? C0 : (z == 1 ? C1 : C2));
                    dst[(((size_t)(b * H + hh)) * T + t2) * HS + e] = __float2bfloat16(v);
                }
            }
        }
    }
}

// ---------------------------------------------------------------------------
// MFMA flash attention, bf16, KVBLK=128, double-buffered K/V staging with
// counted vmcnt. 80 KB LDS -> 2 blocks/CU. grid (T/64, B*H), 4 waves.
// ---------------------------------------------------------------------------
template<int CAUSAL>
__global__ __launch_bounds__(256) void attn_mfma_kernel(
        const short* __restrict__ q, const short* __restrict__ k,
        const short* __restrict__ vt, __hip_bfloat16* __restrict__ att) {
    __shared__ __align__(16) short Ks[2][128 * 64];
    __shared__ __align__(16) short Vs[2][64 * 128];
    __shared__ __align__(16) short Ps[4][16 * 128];
    int bh = blockIdx.y;
    int bI = bh >> 4, h = bh & 15;
    int tix = blockIdx.x;
    if (CAUSAL) tix = (tix & 1) ? (15 - (tix >> 1)) : (tix >> 1);
    int t0 = tix * 64;
    int tid = threadIdx.x;
    int lane = tid & 63, w = tid >> 6;
    int l15 = lane & 15, l16 = lane >> 4;

    const short* Qg = q + ((size_t)bh * T + t0 + w * 16 + l15) * HS + l16 * 8;
    bf16x8 qf0 = *(const bf16x8*)Qg;
    bf16x8 qf1 = *(const bf16x8*)(Qg + 32);

    const char* Kg = (const char*)(k + (size_t)bh * T * HS);
    const char* Vg = (const char*)(vt + (size_t)bh * HS * T);

    float m_run[4] = {-1e30f, -1e30f, -1e30f, -1e30f};
    float l_run[4] = {0.f, 0.f, 0.f, 0.f};
    f32x4 acc_o[4] = {};
    char* Pw = (char*)Ps[w];
    int pswz = l15 << 4;

    auto stageKV = [&](int buf, int s0) {
        #pragma unroll
        for (int i = 0; i < 4; ++i) {
            int o = i * 4096 + tid * 16;
            int row = o >> 7, bir = o & 127;
            gload16(Kg + (size_t)(s0 + row) * 128 + (bir ^ ((row & 7) << 4)),
                    (char*)Ks[buf] + o);
        }
        #pragma unroll
        for (int i = 0; i < 4; ++i) {
            int o = i * 4096 + tid * 16;
            int row = o >> 8, bb = o & 255;
            gload16(Vg + (size_t)row * 2048 + s0 * 2 + (bb ^ ((row & 15) << 4)),
                    (char*)Vs[buf] + o);
        }
    };

    int n_tiles = CAUSAL ? (t0 / 128 + 1) : (T / 128);
    stageKV(0, 0);
    for (int it = 0; it < n_tiles; ++it) {
        int buf = it & 1;
        int s0 = it * 128;
        if (it + 1 < n_tiles) {
            stageKV(buf ^ 1, (it + 1) * 128);
            asm volatile("s_waitcnt vmcnt(8)" ::: "memory");
        } else {
            asm volatile("s_waitcnt vmcnt(0)" ::: "memory");
        }
        __builtin_amdgcn_sched_barrier(0);
        __builtin_amdgcn_s_barrier();
        __builtin_amdgcn_sched_barrier(0);

        f32x4 acc_s[8] = {};
        __builtin_amdgcn_s_setprio(1);
        #pragma unroll
        for (int c = 0; c < 8; ++c) {
            int row = c * 16 + l15;
            const char* kb_ = (const char*)Ks[buf] + row * 128;
            int swz = (row & 7) << 4;
            bf16x8 kf0 = *(const bf16x8*)(kb_ + ((l16 * 16) ^ swz));
            bf16x8 kf1 = *(const bf16x8*)(kb_ + ((64 + l16 * 16) ^ swz));
            acc_s[c] = __builtin_amdgcn_mfma_f32_16x16x32_bf16(qf0, kf0, acc_s[c], 0, 0, 0);
            acc_s[c] = __builtin_amdgcn_mfma_f32_16x16x32_bf16(qf1, kf1, acc_s[c], 0, 0, 0);
        }
        __builtin_amdgcn_s_setprio(0);

        bool domask = CAUSAL && (it == n_tiles - 1);
        #pragma unroll
        for (int r = 0; r < 4; ++r) {
            float sc[8];
            #pragma unroll
            for (int c = 0; c < 8; ++c) {
                float s = acc_s[c][r];
                if (domask && (s0 + c * 16 + l15) > (t0 + w * 16 + l16 * 4 + r)) s = -1e30f;
                sc[c] = s;
            }
            float tm = fmaxf(fmaxf(fmaxf(sc[0], sc[1]), fmaxf(sc[2], sc[3])),
                             fmaxf(fmaxf(sc[4], sc[5]), fmaxf(sc[6], sc[7])));
            tm = fmaxf(tm, __shfl_xor(tm, 1, 16));
            tm = fmaxf(tm, __shfl_xor(tm, 2, 16));
            tm = fmaxf(tm, __shfl_xor(tm, 4, 16));
            tm = fmaxf(tm, __shfl_xor(tm, 8, 16));
            float mn = fmaxf(m_run[r], tm);
            int prow = l16 * 4 + r;
            int pswzr = prow << 4;
            float ls = 0.f;
            #pragma unroll
            for (int c = 0; c < 8; ++c) {
                float pv = __expf(0.125f * (sc[c] - mn));
                int pbyte = prow * 256 + (((c * 16 + l15) * 2) ^ pswzr);
                *(__hip_bfloat16*)(Pw + pbyte) = __float2bfloat16(pv);
                ls += pv;
            }
            ls += __shfl_xor(ls, 1, 16);
            ls += __shfl_xor(ls, 2, 16);
            ls += __shfl_xor(ls, 4, 16);
            ls += __shfl_xor(ls, 8, 16);
            float alpha = __expf(0.125f * (m_run[r] - mn));
            l_run[r] = l_run[r] * alpha + ls;
            m_run[r] = mn;
            acc_o[0][r] *= alpha; acc_o[1][r] *= alpha;
            acc_o[2][r] *= alpha; acc_o[3][r] *= alpha;
        }

        const char* Pb = Pw + l15 * 256;
        bf16x8 pa[4];
        #pragma unroll
        for (int tt = 0; tt < 4; ++tt)
            pa[tt] = *(const bf16x8*)(Pb + ((tt * 64 + l16 * 16) ^ pswz));
        __builtin_amdgcn_s_setprio(1);
        #pragma unroll
        for (int ni = 0; ni < 4; ++ni) {
            int row = ni * 16 + l15;
            const char* vb_ = (const char*)Vs[buf] + row * 256;
            int swz = (row & 15) << 4;
            #pragma unroll
            for (int tt = 0; tt < 4; ++tt) {
                bf16x8 vf = *(const bf16x8*)(vb_ + ((tt * 64 + l16 * 16) ^ swz));
                acc_o[ni] = __builtin_amdgcn_mfma_f32_16x16x32_bf16(pa[tt], vf, acc_o[ni], 0, 0, 0);
            }
        }
        __builtin_amdgcn_s_setprio(0);
        __builtin_amdgcn_s_barrier();
        __builtin_amdgcn_sched_barrier(0);
    }

    float inv[4];
    #pragma unroll
    for (int r = 0; r < 4; ++r) inv[r] = 1.0f / l_run[r];
    #pragma unroll
    for (int ni = 0; ni < 4; ++ni) {
        #pragma unroll
        for (int r = 0; r < 4; ++r) {
            size_t orow = ((size_t)(bI * T) + t0 + w * 16 + l16 * 4 + r) * D
                        + h * HS + ni * 16 + l15;
            att[orow] = __float2bfloat16(acc_o[ni][r] * inv[r]);
        }
    }
}

// ---------------------------------------------------------------------------
extern "C" void kernel_launch(void* const* d_in, const int* in_sizes, int n_in,
                              void* d_out, int out_size, void* d_ws, size_t ws_size,
                              hipStream_t stream) {
    const int*   idx     = (const int*)d_in[0];
    const float* tok_emb = (const float*)d_in[1];
    const float* pos_emb = (const float*)d_in[2];
    const float* Wq_u = (const float*)d_in[3],  *bq_u = (const float*)d_in[4];
    const float* Wk_u = (const float*)d_in[5],  *bk_u = (const float*)d_in[6];
    const float* Wv_u = (const float*)d_in[7],  *bv_u = (const float*)d_in[8];
    const float* Wp_u = (const float*)d_in[9],  *bp_u = (const float*)d_in[10];
    const float* Wq_m = (const float*)d_in[11], *bq_m = (const float*)d_in[12];
    const float* Wk_m = (const float*)d_in[13], *bk_m = (const float*)d_in[14];
    const float* Wv_m = (const float*)d_in[15], *bv_m = (const float*)d_in[16];
    const float* Wp_m = (const float*)d_in[17], *bp_m = (const float*)d_in[18];
    const float* W1   = (const float*)d_in[19], *b1   = (const float*)d_in[20];
    const float* W2   = (const float*)d_in[21], *b2   = (const float*)d_in[22];
    const float* lnf_g = (const float*)d_in[23], *lnf_b = (const float*)d_in[24];
    const float* n1_g  = (const float*)d_in[25], *n1_b  = (const float*)d_in[26];
    const float* n2_g  = (const float*)d_in[27], *n2_b  = (const float*)d_in[28];
    const float* nf_g  = (const float*)d_in[29], *nf_b  = (const float*)d_in[30];
    const float* Wfin  = (const float*)d_in[31], *bfin  = (const float*)d_in[32];
    float* out = (float*)d_out;

    char* p = (char*)d_ws;
    auto alloc = [&](size_t bytes) { char* r = p; p += (bytes + 255) & ~255ull; return r; };
    float* x    = (float*)alloc((size_t)M * D * 4);
    float* x2   = (float*)alloc((size_t)M * D * 4);
    float* w2p  = (float*)alloc((size_t)4 * M * D * 4);
    short* qbf  = (short*)alloc((size_t)M * D * 2);
    short* kbf  = (short*)alloc((size_t)M * D * 2);
    short* vbf  = (short*)alloc((size_t)M * D * 2);
    short* vtb  = (short*)alloc((size_t)M * D * 2);
    short* xnb  = (short*)alloc((size_t)M * D * 2);
    short* attb = (short*)alloc((size_t)M * D * 2);
    short* hb   = (short*)alloc((size_t)M * DFF * 2);
    short* WqkvT= (short*)alloc((size_t)2 * 3 * H * HS * D * 2);
    short* WpT  = (short*)alloc((size_t)2 * D * D * 2);
    short* W1T  = (short*)alloc((size_t)D * DFF * 2);
    short* W2T  = (short*)alloc((size_t)DFF * D * 2);
    short* WfT  = (short*)alloc((size_t)D * V * 2);

    embed_ln_kernel<<<M / 4, 256, 0, stream>>>(idx, tok_emb, pos_emb,
        n1_g, n1_b, x, (__hip_bfloat16*)xnb);
    transpose_bf16_kernel<<<dim3(V / 32, D / 32), 256, 0, stream>>>(
        Wfin, (__hip_bfloat16*)WfT, D, V);

    for (int l = 0; l < LNUM; ++l) {
        const float *n1g = n1_g + l * D, *n1b = n1_b + l * D;
        const float *n2g = n2_g + l * D, *n2b = n2_b + l * D;
        const float *lfg = lnf_g + l * D, *lfb = lnf_b + l * D;
        const float *W1l = W1 + (size_t)l * D * DFF, *b1l = b1 + l * DFF;
        const float *W2l = W2 + (size_t)l * DFF * D, *b2l = b2 + l * D;
        trans_w12_kernel<<<dim3(160, 32, 2), 256, 0, stream>>>(
            W1l, W2l, W1T, W2T);
        trans_qkvp2_kernel<<<dim3(32, 32, 8), 256, 0, stream>>>(
            Wq_u + (size_t)l * H * D * HS, Wk_u + (size_t)l * H * D * HS,
            Wv_u + (size_t)l * H * D * HS, Wp_u + (size_t)l * D * D,
            Wq_m + (size_t)l * H * D * HS, Wk_m + (size_t)l * H * D * HS,
            Wv_m + (size_t)l * H * D * HS, Wp_m + (size_t)l * D * D,
            WqkvT, WpT);
        for (int half = 0; half < 2; ++half) {
            const float *bq_, *bk_, *bv_, *bp_;
            if (half == 0) { bq_ = bq_u; bk_ = bk_u; bv_ = bv_u; bp_ = bp_u; }
            else           { bq_ = bq_m; bk_ = bk_m; bv_ = bv_m; bp_ = bp_m; }
            bq_ += l * H * HS;  bk_ += l * H * HS;  bv_ += l * H * HS;  bp_ += l * D;
            const short* WqkvTh = WqkvT + (size_t)half * 3 * H * HS * D;
            const short* WpTh   = WpT + (size_t)half * D * D;

            // q,k,v = xn @ Wqkv -> bf16 [B,H,T,HS]
            mm_bf16_kernel<128, 3><<<dim3(M / 128, 3072 / 128), 256, 0, stream>>>(
                xnb, WqkvTh, bq_, bk_, bv_, nullptr,
                (float*)qbf, (float*)kbf, (float*)vbf, nullptr, 3072, D, D);
            transpose_v_kernel<<<dim3(HS / 32, T / 32, BB * H), 256, 0, stream>>>(vbf, vtb);
            if (half == 0)
                attn_mfma_kernel<0><<<dim3(T / 64, BB * H), 256, 0, stream>>>(
                    qbf, kbf, vtb, (__hip_bfloat16*)attb);
            else
                attn_mfma_kernel<1><<<dim3(T / 64, BB * H), 256, 0, stream>>>(
                    qbf, kbf, vtb, (__hip_bfloat16*)attb);
            // att @ Wp  split-K x2 -> partials (512 blocks)
            mm_bf16_kernel<64, 4><<<dim3(M / 64, D / 128, 2), 256, 0, stream>>>(
                attb, WpTh, nullptr, nullptr, nullptr, nullptr, w2p, nullptr, nullptr,
                nullptr, D, D / 2, D);
            // proj tail: x2 = x + p0 + p1 + bp ; xn = ln(x2, n2)
            proj_tail_kernel<<<M / 4, 256, 0, stream>>>(
                w2p, bp_, x, n2g, n2b, x2, (__hip_bfloat16*)xnb);
            // h = leaky(xn @ W1 + b1) -> bf16  (256^2 2-phase)
            mm256_kernel<2><<<(M / 256) * (DFF / 256), 512, 0, stream>>>(
                xnb, W1T, b1l, nullptr, (__hip_bfloat16*)hb, DFF, D, D);
            // W2 split-K x4 -> partials (512 blocks, 2/CU)
            mm_bf16_kernel<128, 4><<<dim3(M / 128, D / 128, 4), 256, 0, stream>>>(
                hb, W2T, nullptr, nullptr, nullptr, nullptr, w2p, nullptr, nullptr,
                nullptr, D, DFF / 4, DFF);
            const float* og = half ? n2g : n1g;
            const float* ob = half ? n2b : n1b;
            const float* gn; const float* bn;
            if (half == 0)      { gn = n1g; bn = n1b; }
            else if (l < LNUM-1){ gn = n1_g + (l+1)*D; bn = n1_b + (l+1)*D; }
            else                { gn = nf_g; bn = nf_b; }
            ffn_tail_kernel<4><<<M / 4, 256, 0, stream>>>(
                w2p, b2l, lfg, lfb, og, ob, x2, x, gn, bn, (__hip_bfloat16*)xnb);
        }
    }
    // vocab head
    mm256_kernel<0><<<(M / 256) * (V / 256), 512, 0, stream>>>(
        xnb, WfT, bfin, out, nullptr, V, D, D);
}

// Round 19
// 1459.223 us; speedup vs baseline: 1.0672x; 1.0277x over previous
//
#include <hip/hip_runtime.h>
#include <hip/hip_bf16.h>
#include <math.h>

#define LNUM 4
#define H 16
#define D 1024
#define HS 64
#define DFF 5120
#define V 32000
#define BB 2
#define T 1024
#define M (BB*T)          // 2048 token rows
#define EPS 1e-5f

typedef __attribute__((ext_vector_type(8))) short bf16x8;
typedef __attribute__((ext_vector_type(4))) float f32x4;

// async global->LDS, 16B per lane (wave-uniform LDS base + lane*16)
__device__ __forceinline__ void gload16(const void* g, void* l) {
    __builtin_amdgcn_global_load_lds(
        (const __attribute__((address_space(1))) void*)g,
        (__attribute__((address_space(3))) void*)l, 16, 0, 0);
}

__device__ __forceinline__ float wred_sum(float v) {
    #pragma unroll
    for (int off = 32; off; off >>= 1) v += __shfl_xor(v, off, 64);
    return v;
}

__device__ __forceinline__ float b2f(unsigned short u) {
    union { unsigned int i; float f; } c;
    c.i = (unsigned int)u << 16;
    return c.f;
}

// ---------------------------------------------------------------------------
// embed + first pre-attn LN fused (wave-per-row, 4 rows/block)
// ---------------------------------------------------------------------------
__global__ __launch_bounds__(256) void embed_ln_kernel(const int* __restrict__ idx,
        const float* __restrict__ tok, const float* __restrict__ pos,
        const float* __restrict__ g, const float* __restrict__ b,
        float* __restrict__ x, __hip_bfloat16* __restrict__ xn) {
    int w = threadIdx.x >> 6, lane = threadIdx.x & 63;
    int row = blockIdx.x * 4 + w;
    int t = row & (T - 1);
    int tok_id = idx[row];
    const float* tp = tok + (size_t)tok_id * D;
    const float* pp = pos + (size_t)t * D;
    float4 xv[4];
    float s = 0.f;
    #pragma unroll
    for (int c = 0; c < 4; ++c) {
        int j = c * 256 + lane * 4;
        float4 a = *(const float4*)&tp[j];
        float4 p = *(const float4*)&pp[j];
        a.x += p.x; a.y += p.y; a.z += p.z; a.w += p.w;
        *(float4*)&x[(size_t)row * D + j] = a;
        xv[c] = a;
        s += a.x + a.y + a.z + a.w;
    }
    float mu = wred_sum(s) * (1.0f / D);
    float vs = 0.f;
    #pragma unroll
    for (int c = 0; c < 4; ++c) {
        xv[c].x -= mu; xv[c].y -= mu; xv[c].z -= mu; xv[c].w -= mu;
        vs += xv[c].x*xv[c].x + xv[c].y*xv[c].y + xv[c].z*xv[c].z + xv[c].w*xv[c].w;
    }
    float rs = rsqrtf(wred_sum(vs) * (1.0f / D) + EPS);
    #pragma unroll
    for (int c = 0; c < 4; ++c) {
        int j = c * 256 + lane * 4;
        float4 gv = *(const float4*)&g[j];
        float4 bv = *(const float4*)&b[j];
        union { ushort4 u4; __hip_bfloat16 h[4]; } pk;
        pk.h[0] = __float2bfloat16(xv[c].x * rs * gv.x + bv.x);
        pk.h[1] = __float2bfloat16(xv[c].y * rs * gv.y + bv.y);
        pk.h[2] = __float2bfloat16(xv[c].z * rs * gv.z + bv.z);
        pk.h[3] = __float2bfloat16(xv[c].w * rs * gv.w + bv.w);
        *(ushort4*)&xn[(size_t)row * D + j] = pk.u4;
    }
}

// ---------------------------------------------------------------------------
// proj tail, fused: x2 = x + p0 + p1 + bp ; xn = ln(x2, n2) -> bf16
// (partials are bf16)
// ---------------------------------------------------------------------------
__global__ __launch_bounds__(256) void proj_tail_kernel(
        const unsigned short* __restrict__ part, const float* __restrict__ bp,
        const float* __restrict__ res,
        const float* __restrict__ g, const float* __restrict__ b,
        float* __restrict__ x2out, __hip_bfloat16* __restrict__ xnout) {
    const size_t MD = (size_t)M * D;
    int w = threadIdx.x >> 6, lane = threadIdx.x & 63;
    int row = blockIdx.x * 4 + w;
    size_t ro = (size_t)row * D;
    float4 f[4];
    float s = 0.f;
    #pragma unroll
    for (int c = 0; c < 4; ++c) {
        int j = c * 256 + lane * 4;
        float4 rv = *(const float4*)&res[ro + j];
        ushort4 p0 = *(const ushort4*)&part[ro + j];
        ushort4 p1 = *(const ushort4*)&part[MD + ro + j];
        float4 bv = *(const float4*)&bp[j];
        float4 a;
        a.x = rv.x + b2f(p0.x) + b2f(p1.x) + bv.x;
        a.y = rv.y + b2f(p0.y) + b2f(p1.y) + bv.y;
        a.z = rv.z + b2f(p0.z) + b2f(p1.z) + bv.z;
        a.w = rv.w + b2f(p0.w) + b2f(p1.w) + bv.w;
        *(float4*)&x2out[ro + j] = a;
        f[c] = a;
        s += a.x + a.y + a.z + a.w;
    }
    float mu = wred_sum(s) * (1.0f / D);
    float vs = 0.f;
    #pragma unroll
    for (int c = 0; c < 4; ++c) {
        f[c].x -= mu; f[c].y -= mu; f[c].z -= mu; f[c].w -= mu;
        vs += f[c].x*f[c].x + f[c].y*f[c].y + f[c].z*f[c].z + f[c].w*f[c].w;
    }
    float rs = rsqrtf(wred_sum(vs) * (1.0f / D) + EPS);
    #pragma unroll
    for (int c = 0; c < 4; ++c) {
        int j = c * 256 + lane * 4;
        float4 gv = *(const float4*)&g[j];
        float4 bv = *(const float4*)&b[j];
        union { ushort4 u4; __hip_bfloat16 h[4]; } pk;
        pk.h[0] = __float2bfloat16(f[c].x * rs * gv.x + bv.x);
        pk.h[1] = __float2bfloat16(f[c].y * rs * gv.y + bv.y);
        pk.h[2] = __float2bfloat16(f[c].z * rs * gv.z + bv.z);
        pk.h[3] = __float2bfloat16(f[c].w * rs * gv.w + bv.w);
        *(ushort4*)&xnout[ro + j] = pk.u4;
    }
}

// ---------------------------------------------------------------------------
// FFN tail, fused:  f = sum(bf16 partials)+b2 ;
// x = res + ln(ln(f,g1,b1),g2,b2g) ; xn = ln(x, gn, bn) -> bf16
// ---------------------------------------------------------------------------
template<int NP>
__global__ __launch_bounds__(256) void ffn_tail_kernel(
        const unsigned short* __restrict__ part, const float* __restrict__ b2,
        const float* __restrict__ g1, const float* __restrict__ b1,
        const float* __restrict__ g2, const float* __restrict__ b2g,
        const float* __restrict__ res, float* __restrict__ xout,
        const float* __restrict__ gn, const float* __restrict__ bn,
        __hip_bfloat16* __restrict__ xnout) {
    const size_t MD = (size_t)M * D;
    int w = threadIdx.x >> 6, lane = threadIdx.x & 63;
    int row = blockIdx.x * 4 + w;
    size_t ro = (size_t)row * D;
    float4 f[4];
    float s = 0.f;
    #pragma unroll
    for (int c = 0; c < 4; ++c) {
        int j = c * 256 + lane * 4;
        float4 acc = *(const float4*)&b2[j];
        #pragma unroll
        for (int pI = 0; pI < NP; ++pI) {
            ushort4 pv = *(const ushort4*)&part[pI * MD + ro + j];
            acc.x += b2f(pv.x); acc.y += b2f(pv.y);
            acc.z += b2f(pv.z); acc.w += b2f(pv.w);
        }
        f[c] = acc;
        s += acc.x + acc.y + acc.z + acc.w;
    }
    float mu = wred_sum(s) * (1.0f / D);
    float vs = 0.f;
    #pragma unroll
    for (int c = 0; c < 4; ++c) {
        f[c].x -= mu; f[c].y -= mu; f[c].z -= mu; f[c].w -= mu;
        vs += f[c].x*f[c].x + f[c].y*f[c].y + f[c].z*f[c].z + f[c].w*f[c].w;
    }
    float rs = rsqrtf(wred_sum(vs) * (1.0f / D) + EPS);
    float s2 = 0.f;
    #pragma unroll
    for (int c = 0; c < 4; ++c) {
        int j = c * 256 + lane * 4;
        float4 gv = *(const float4*)&g1[j];
        float4 bv = *(const float4*)&b1[j];
        f[c].x = f[c].x * rs * gv.x + bv.x;
        f[c].y = f[c].y * rs * gv.y + bv.y;
        f[c].z = f[c].z * rs * gv.z + bv.z;
        f[c].w = f[c].w * rs * gv.w + bv.w;
        s2 += f[c].x + f[c].y + f[c].z + f[c].w;
    }
    float mu2 = wred_sum(s2) * (1.0f / D);
    float vs2 = 0.f;
    #pragma unroll
    for (int c = 0; c < 4; ++c) {
        f[c].x -= mu2; f[c].y -= mu2; f[c].z -= mu2; f[c].w -= mu2;
        vs2 += f[c].x*f[c].x + f[c].y*f[c].y + f[c].z*f[c].z + f[c].w*f[c].w;
    }
    float rs2 = rsqrtf(wred_sum(vs2) * (1.0f / D) + EPS);
    float s3 = 0.f;
    #pragma unroll
    for (int c = 0; c < 4; ++c) {
        int j = c * 256 + lane * 4;
        float4 gv = *(const float4*)&g2[j];
        float4 bv = *(const float4*)&b2g[j];
        float4 rv = *(const float4*)&res[ro + j];
        f[c].x = rv.x + f[c].x * rs2 * gv.x + bv.x;
        f[c].y = rv.y + f[c].y * rs2 * gv.y + bv.y;
        f[c].z = rv.z + f[c].z * rs2 * gv.z + bv.z;
        f[c].w = rv.w + f[c].w * rs2 * gv.w + bv.w;
        *(float4*)&xout[ro + j] = f[c];
        s3 += f[c].x + f[c].y + f[c].z + f[c].w;
    }
    float mu3 = wred_sum(s3) * (1.0f / D);
    float vs3 = 0.f;
    #pragma unroll
    for (int c = 0; c < 4; ++c) {
        f[c].x -= mu3; f[c].y -= mu3; f[c].z -= mu3; f[c].w -= mu3;
        vs3 += f[c].x*f[c].x + f[c].y*f[c].y + f[c].z*f[c].z + f[c].w*f[c].w;
    }
    float rs3 = rsqrtf(wred_sum(vs3) * (1.0f / D) + EPS);
    #pragma unroll
    for (int c = 0; c < 4; ++c) {
        int j = c * 256 + lane * 4;
        float4 gv = *(const float4*)&gn[j];
        float4 bv = *(const float4*)&bn[j];
        union { ushort4 u4; __hip_bfloat16 h[4]; } pk;
        pk.h[0] = __float2bfloat16(f[c].x * rs3 * gv.x + bv.x);
        pk.h[1] = __float2bfloat16(f[c].y * rs3 * gv.y + bv.y);
        pk.h[2] = __float2bfloat16(f[c].z * rs3 * gv.z + bv.z);
        pk.h[3] = __float2bfloat16(f[c].w * rs3 * gv.w + bv.w);
        *(ushort4*)&xnout[ro + j] = pk.u4;
    }
}

// ---------------------------------------------------------------------------
// tiled transpose + fp32->bf16: in [R][C] f32 -> out [C][R] bf16 (Wfin)
// ---------------------------------------------------------------------------
__global__ __launch_bounds__(256) void transpose_bf16_kernel(
        const float* __restrict__ in, __hip_bfloat16* __restrict__ out,
        int R, int C) {
    __shared__ float t[32][33];
    int tx = threadIdx.x & 31, ty = threadIdx.x >> 5;
    int c0 = blockIdx.x * 32, r0 = blockIdx.y * 32;
    #pragma unroll
    for (int i = 0; i < 4; ++i)
        t[ty + i * 8][tx] = in[(size_t)(r0 + ty + i * 8) * C + c0 + tx];
    __syncthreads();
    #pragma unroll
    for (int i = 0; i < 4; ++i)
        out[(size_t)(c0 + ty + i * 8) * R + r0 + tx] = __float2bfloat16(t[tx][ty + i * 8]);
}

// ---------------------------------------------------------------------------
// per-LAYER weight prep (both halves) in ONE launch: grid (32, 32, 8)
// ---------------------------------------------------------------------------
__global__ __launch_bounds__(256) void trans_qkvp2_kernel(
        const float* __restrict__ Wq0, const float* __restrict__ Wk0,
        const float* __restrict__ Wv0, const float* __restrict__ Wp0,
        const float* __restrict__ Wq1, const float* __restrict__ Wk1,
        const float* __restrict__ Wv1, const float* __restrict__ Wp1,
        short* __restrict__ qkvT, short* __restrict__ WpT) {
    __shared__ float t[32][33];
    int tx = threadIdx.x & 31, ty = threadIdx.x >> 5;
    int z = blockIdx.z;
    int half = z >> 2, which = z & 3;
    const float* in;
    __hip_bfloat16* out;
    int inC, outC, c0;
    int r0 = blockIdx.y * 32;
    if (which < 3) {
        int c0g = blockIdx.x * 32;
        int h = c0g >> 6;
        c0 = c0g & 63;
        const float* base = which == 0 ? (half ? Wq1 : Wq0)
                          : which == 1 ? (half ? Wk1 : Wk0)
                                       : (half ? Wv1 : Wv0);
        in = base + (size_t)h * D * HS;
        out = (__hip_bfloat16*)qkvT + (size_t)half * 3 * H * HS * D
            + ((size_t)which * H + h) * HS * D;
        inC = HS; outC = D;
    } else {
        c0 = blockIdx.x * 32;
        in = half ? Wp1 : Wp0;
        out = (__hip_bfloat16*)WpT + (size_t)half * D * D;
        inC = D; outC = D;
    }
    #pragma unroll
    for (int i = 0; i < 4; ++i)
        t[ty + i * 8][tx] = in[(size_t)(r0 + ty + i * 8) * inC + c0 + tx];
    __syncthreads();
    #pragma unroll
    for (int i = 0; i < 4; ++i)
        out[(size_t)(c0 + ty + i * 8) * outC + r0 + tx] = __float2bfloat16(t[tx][ty + i * 8]);
}

// ---------------------------------------------------------------------------
// per-layer W1+W2 transpose in ONE launch: grid (160, 32, 2)
// ---------------------------------------------------------------------------
__global__ __launch_bounds__(256) void trans_w12_kernel(
        const float* __restrict__ W1, const float* __restrict__ W2,
        short* __restrict__ W1T, short* __restrict__ W2T) {
    __shared__ float t[32][33];
    int tx = threadIdx.x & 31, ty = threadIdx.x >> 5;
    int z = blockIdx.z;
    const float* in; __hip_bfloat16* out;
    int inC, outC, r0, c0;
    if (z == 0) { in = W1; out = (__hip_bfloat16*)W1T; inC = DFF; outC = D;
                  r0 = blockIdx.y * 32; c0 = blockIdx.x * 32; }
    else        { in = W2; out = (__hip_bfloat16*)W2T; inC = D; outC = DFF;
                  r0 = blockIdx.x * 32; c0 = blockIdx.y * 32; }
    #pragma unroll
    for (int i = 0; i < 4; ++i)
        t[ty + i * 8][tx] = in[(size_t)(r0 + ty + i * 8) * inC + c0 + tx];
    __syncthreads();
    #pragma unroll
    for (int i = 0; i < 4; ++i)
        out[(size_t)(c0 + ty + i * 8) * outC + r0 + tx] = __float2bfloat16(t[tx][ty + i * 8]);
}

// ---------------------------------------------------------------------------
// bf16->bf16 transpose for V: in [T][HS] per bh -> out [HS][T]
// ---------------------------------------------------------------------------
__global__ __launch_bounds__(256) void transpose_v_kernel(const short* __restrict__ in,
        short* __restrict__ out) {
    __shared__ short t[32][33];
    int z = blockIdx.z;
    in  += (size_t)z * T * HS;
    out += (size_t)z * HS * T;
    int tx = threadIdx.x & 31, ty = threadIdx.x >> 5;
    int c0 = blockIdx.x * 32, r0 = blockIdx.y * 32;
    #pragma unroll
    for (int i = 0; i < 4; ++i)
        t[ty + i * 8][tx] = in[(size_t)(r0 + ty + i * 8) * HS + c0 + tx];
    __syncthreads();
    #pragma unroll
    for (int i = 0; i < 4; ++i)
        out[(size_t)(c0 + ty + i * 8) * T + r0 + tx] = t[tx][ty + i * 8];
}

// ---------------------------------------------------------------------------
// 256x256 bf16 MFMA GEMM, 2 phases per K-tile (BK=64). 512 thr = 8 waves.
// EPI: 0 f32+bias -> C0 ; 2 leaky -> bf16 Cbf.  M fixed = 2048 (8 M-tiles).
// ---------------------------------------------------------------------------
template<int EPI>
__global__ __launch_bounds__(512, 2) void mm256_kernel(
        const short* __restrict__ A, const short* __restrict__ BT,
        const float* __restrict__ bias0, float* __restrict__ C0,
        __hip_bfloat16* __restrict__ Cbf, int N, int Kloop, int lda) {
    __shared__ __align__(16) char LA[2][2][256 * 64];
    __shared__ __align__(16) char LB[2][2][256 * 64];
    int tid = threadIdx.x;
    int lane = tid & 63, wid = tid >> 6;
    int wr = wid >> 2, wc = wid & 3;
    int l15 = lane & 15, l16 = lane >> 4;

    int nwg = gridDim.x;
    int bid = blockIdx.x;
    int q = nwg >> 3, r = nwg & 7;
    int xcd = bid & 7, loc = bid >> 3;
    int wg = (xcd < r ? xcd * (q + 1) : r * (q + 1) + (xcd - r) * q) + loc;
    int m0 = (wg & 7) * 256;
    int n0 = (wg >> 3) * 256;

    const size_t lda2 = (size_t)lda * 2;
    const char* Agc = (const char*)A + (size_t)m0 * lda2;
    const char* Bgc = (const char*)BT + (size_t)n0 * lda2;

    f32x4 acc[8][4] = {};
    bf16x8 af[8], bfr[4];

    auto stA = [&](int buf, int kh, int kt) {
        #pragma unroll
        for (int i = 0; i < 2; ++i) {
            int o = i * 8192 + tid * 16;
            int row = o >> 6, col = o & 63;
            gload16(Agc + (size_t)row * lda2 + kt * 128 + kh * 64 +
                    (col ^ (((row >> 1) & 3) << 4)), LA[buf][kh] + o);
        }
    };
    auto stB = [&](int buf, int kh, int kt) {
        #pragma unroll
        for (int i = 0; i < 2; ++i) {
            int o = i * 8192 + tid * 16;
            int row = o >> 6, col = o & 63;
            gload16(Bgc + (size_t)row * lda2 + kt * 128 + kh * 64 +
                    (col ^ (((row >> 1) & 3) << 4)), LB[buf][kh] + o);
        }
    };
    auto rdA = [&](int buf, int kk) {
        #pragma unroll
        for (int mf = 0; mf < 8; ++mf) {
            int row = wr * 128 + mf * 16 + l15;
            af[mf] = *(const bf16x8*)(LA[buf][kk] + row * 64 +
                      ((l16 * 16) ^ (((row >> 1) & 3) << 4)));
        }
    };
    auto rdB4 = [&](int buf, int kk) {
        #pragma unroll
        for (int nf = 0; nf < 4; ++nf) {
            int row = wc * 64 + nf * 16 + l15;
            bfr[nf] = *(const bf16x8*)(LB[buf][kk] + row * 64 +
                       ((l16 * 16) ^ (((row >> 1) & 3) << 4)));
        }
    };
    auto mfma32 = [&]() {
        __builtin_amdgcn_s_setprio(1);
        #pragma unroll
        for (int mf = 0; mf < 8; ++mf)
            #pragma unroll
            for (int nf = 0; nf < 4; ++nf)
                acc[mf][nf] = __builtin_amdgcn_mfma_f32_16x16x32_bf16(
                    af[mf], bfr[nf], acc[mf][nf], 0, 0, 0);
        __builtin_amdgcn_s_setprio(0);
    };

    const int NT = Kloop / 64;
    stA(0, 0, 0); stB(0, 0, 0); stA(0, 1, 0); stB(0, 1, 0);
    stA(1, 0, 1); stB(1, 0, 1);
    asm volatile("s_waitcnt vmcnt(4)" ::: "memory");
    __builtin_amdgcn_sched_barrier(0);
    __builtin_amdgcn_s_barrier();
    __builtin_amdgcn_sched_barrier(0);

    for (int t = 0; t < NT; ++t) {
        int buf = t & 1;
        rdA(buf, 0); rdB4(buf, 0);
        if (t + 1 < NT) { stA(buf ^ 1, 1, t + 1); stB(buf ^ 1, 1, t + 1); }
        mfma32();
        __builtin_amdgcn_sched_barrier(0);
        __builtin_amdgcn_s_barrier();
        __builtin_amdgcn_sched_barrier(0);
        rdA(buf, 1); rdB4(buf, 1);
        if (t + 2 < NT) { stA(buf, 0, t + 2); stB(buf, 0, t + 2); }
        mfma32();
        if (t + 2 < NT) { asm volatile("s_waitcnt vmcnt(4)" ::: "memory"); }
        else            { asm volatile("s_waitcnt vmcnt(0)" ::: "memory"); }
        __builtin_amdgcn_sched_barrier(0);
        __builtin_amdgcn_s_barrier();
        __builtin_amdgcn_sched_barrier(0);
    }

    #pragma unroll
    for (int mf = 0; mf < 8; ++mf) {
        #pragma unroll
        for (int nf = 0; nf < 4; ++nf) {
            int col = n0 + wc * 64 + nf * 16 + l15;
            float bv = bias0[col];
            #pragma unroll
            for (int rr = 0; rr < 4; ++rr) {
                int row = m0 + wr * 128 + mf * 16 + l16 * 4 + rr;
                float v = acc[mf][nf][rr] + bv;
                if (EPI == 0) {
                    C0[(size_t)row * N + col] = v;
                } else {
                    v = v > 0.f ? v : 0.01f * v;
                    Cbf[(size_t)row * N + col] = __float2bfloat16(v);
                }
            }
        }
    }
}

// ---------------------------------------------------------------------------
// bf16 MFMA GEMM (128-tile, double-buffered counted-vmcnt) — qkv/proj/W2.
// EPI: 0 f32 C0 ; 1 +res f32 C0 ; 2 leaky bf16 Cbf ; 3 qkv scatter bf16 ;
//      4 raw partial f32 -> C0 + z*M*N ; 5 raw partial bf16 -> Cbf + z*M*N
// ---------------------------------------------------------------------------
template<int BM, int EPI>
__global__ __launch_bounds__(256) void mm_bf16_kernel(
        const short* __restrict__ A, const short* __restrict__ BT,
        const float* __restrict__ bias0, const float* __restrict__ bias1,
        const float* __restrict__ bias2, const float* __restrict__ res,
        float* __restrict__ C0, float* __restrict__ C1, float* __restrict__ C2,
        __hip_bfloat16* __restrict__ Cbf, int N, int Kloop, int lda) {
    constexpr int MI = BM / 32;
    __shared__ __align__(16) char As[2][BM * 128];
    __shared__ __align__(16) char Bs[2][128 * 128];
    int nwg = gridDim.x * gridDim.y;
    int bid = blockIdx.y * gridDim.x + blockIdx.x;
    int bx = blockIdx.x, by = blockIdx.y;
    if (!(nwg & 7)) {
        int s = (bid & 7) * (nwg >> 3) + (bid >> 3);
        bx = s % gridDim.x; by = s / gridDim.x;
    }
    int tid = threadIdx.x;
    int lane = tid & 63, wid = tid >> 6;
    int wr = wid >> 1, wc = wid & 1;
    int l15 = lane & 15, l16 = lane >> 4;
    int m0 = bx * BM, n0 = by * 128;
    f32x4 acc[MI][4] = {};

    const size_t lda2 = (size_t)lda * 2;
    const char* Agc = (const char*)A + (size_t)m0 * lda2 + (size_t)blockIdx.z * Kloop * 2;
    const char* Bgc = (const char*)BT + (size_t)n0 * lda2 + (size_t)blockIdx.z * Kloop * 2;

    auto stage = [&](int buf, int kbyte) {
        #pragma unroll
        for (int i = 0; i < BM / 32; ++i) {
            int o = i * 4096 + tid * 16;
            int row = o >> 7, col = o & 127;
            gload16(Agc + (size_t)row * lda2 + kbyte + (col ^ ((row & 7) << 4)),
                    As[buf] + o);
        }
        #pragma unroll
        for (int i = 0; i < 4; ++i) {
            int o = i * 4096 + tid * 16;
            int row = o >> 7, col = o & 127;
            gload16(Bgc + (size_t)row * lda2 + kbyte + (col ^ ((row & 7) << 4)),
                    Bs[buf] + o);
        }
    };
    auto compute = [&](int buf) {
        #pragma unroll
        for (int kk = 0; kk < 2; ++kk) {
            bf16x8 af[MI], bfr[4];
            #pragma unroll
            for (int mi = 0; mi < MI; ++mi) {
                int row = wr * (BM / 2) + mi * 16 + l15;
                af[mi] = *(const bf16x8*)(As[buf] + row * 128 +
                          ((kk * 64 + l16 * 16) ^ ((row & 7) << 4)));
            }
            #pragma unroll
            for (int ni = 0; ni < 4; ++ni) {
                int row = wc * 64 + ni * 16 + l15;
                bfr[ni] = *(const bf16x8*)(Bs[buf] + row * 128 +
                          ((kk * 64 + l16 * 16) ^ ((row & 7) << 4)));
            }
            __builtin_amdgcn_s_setprio(1);
            #pragma unroll
            for (int mi = 0; mi < MI; ++mi)
                #pragma unroll
                for (int ni = 0; ni < 4; ++ni)
                    acc[mi][ni] = __builtin_amdgcn_mfma_f32_16x16x32_bf16(
                        af[mi], bfr[ni], acc[mi][ni], 0, 0, 0);
            __builtin_amdgcn_s_setprio(0);
        }
    };

    const int NT = Kloop / 64;
    stage(0, 0);
    stage(1, 128);
    for (int t = 0; t < NT; ++t) {
        if (t < NT - 1) {
            if constexpr (BM == 128) asm volatile("s_waitcnt vmcnt(8)" ::: "memory");
            else                     asm volatile("s_waitcnt vmcnt(6)" ::: "memory");
        } else {
            asm volatile("s_waitcnt vmcnt(0)" ::: "memory");
        }
        __builtin_amdgcn_sched_barrier(0);
        __builtin_amdgcn_s_barrier();
        __builtin_amdgcn_sched_barrier(0);
        compute(t & 1);
        __builtin_amdgcn_s_barrier();
        __builtin_amdgcn_sched_barrier(0);
        if (t + 2 < NT) stage(t & 1, (t + 2) * 128);
    }

    int rbase = m0 + wr * (BM / 2) + l16 * 4;
    int cbase = n0 + wc * 64 + l15;
    size_t zoff = (EPI == 4 || EPI == 5) ? (size_t)blockIdx.z * M * N : 0;
    #pragma unroll
    for (int mi = 0; mi < MI; ++mi) {
        #pragma unroll
        for (int ni = 0; ni < 4; ++ni) {
            int col = cbase + ni * 16;
            float bv = 0.f;
            if (EPI == 3) {
                int z = col >> 10, nn = col & 1023;
                bv = (z == 0 ? bias0 : z == 1 ? bias1 : bias2)[nn];
            } else if (EPI != 4 && EPI != 5) bv = bias0[col];
            #pragma unroll
            for (int r = 0; r < 4; ++r) {
                int row = rbase + mi * 16 + r;
                float v = acc[mi][ni][r] + bv;
                if (EPI == 0) {
                    C0[(size_t)row * N + col] = v;
                } else if (EPI == 1) {
                    C0[(size_t)row * N + col] = v + res[(size_t)row * N + col];
                } else if (EPI == 2) {
                    v = v > 0.f ? v : 0.01f * v;
                    Cbf[(size_t)row * N + col] = __float2bfloat16(v);
                } else if (EPI == 4) {
                    C0[zoff + (size_t)row * N + col] = v;
                } else if (EPI == 5) {
                    Cbf[zoff + (size_t)row * N + col] = __float2bfloat16(v);
                } else {
                    int z = col >> 10;
                    int hh = (col >> 6) & 15, e = col & 63;
                    int b = row >> 10, t2 = row & (T - 1);
                    __hip_bfloat16* dst = (__hip_bfloat16*)(z == 0 ? C0 : (z == 1 ? C1 : C2));
                    dst[(((size_t)(b * H + hh)) * T + t2) * HS + e] = __float2bfloat16(v);
                }
            }
        }
    }
}

// ---------------------------------------------------------------------------
// MFMA flash attention, bf16, KVBLK=128, double-buffered K/V staging with
// counted vmcnt. 80 KB LDS -> 2 blocks/CU. grid (T/64, B*H), 4 waves.
// ---------------------------------------------------------------------------
template<int CAUSAL>
__global__ __launch_bounds__(256) void attn_mfma_kernel(
        const short* __restrict__ q, const short* __restrict__ k,
        const short* __restrict__ vt, __hip_bfloat16* __restrict__ att) {
    __shared__ __align__(16) short Ks[2][128 * 64];
    __shared__ __align__(16) short Vs[2][64 * 128];
    __shared__ __align__(16) short Ps[4][16 * 128];
    int bh = blockIdx.y;
    int bI = bh >> 4, h = bh & 15;
    int tix = blockIdx.x;
    if (CAUSAL) tix = (tix & 1) ? (15 - (tix >> 1)) : (tix >> 1);
    int t0 = tix * 64;
    int tid = threadIdx.x;
    int lane = tid & 63, w = tid >> 6;
    int l15 = lane & 15, l16 = lane >> 4;

    const short* Qg = q + ((size_t)bh * T + t0 + w * 16 + l15) * HS + l16 * 8;
    bf16x8 qf0 = *(const bf16x8*)Qg;
    bf16x8 qf1 = *(const bf16x8*)(Qg + 32);

    const char* Kg = (const char*)(k + (size_t)bh * T * HS);
    const char* Vg = (const char*)(vt + (size_t)bh * HS * T);

    float m_run[4] = {-1e30f, -1e30f, -1e30f, -1e30f};
    float l_run[4] = {0.f, 0.f, 0.f, 0.f};
    f32x4 acc_o[4] = {};
    char* Pw = (char*)Ps[w];
    int pswz = l15 << 4;

    auto stageKV = [&](int buf, int s0) {
        #pragma unroll
        for (int i = 0; i < 4; ++i) {
            int o = i * 4096 + tid * 16;
            int row = o >> 7, bir = o & 127;
            gload16(Kg + (size_t)(s0 + row) * 128 + (bir ^ ((row & 7) << 4)),
                    (char*)Ks[buf] + o);
        }
        #pragma unroll
        for (int i = 0; i < 4; ++i) {
            int o = i * 4096 + tid * 16;
            int row = o >> 8, bb = o & 255;
            gload16(Vg + (size_t)row * 2048 + s0 * 2 + (bb ^ ((row & 15) << 4)),
                    (char*)Vs[buf] + o);
        }
    };

    int n_tiles = CAUSAL ? (t0 / 128 + 1) : (T / 128);
    stageKV(0, 0);
    for (int it = 0; it < n_tiles; ++it) {
        int buf = it & 1;
        int s0 = it * 128;
        if (it + 1 < n_tiles) {
            stageKV(buf ^ 1, (it + 1) * 128);
            asm volatile("s_waitcnt vmcnt(8)" ::: "memory");
        } else {
            asm volatile("s_waitcnt vmcnt(0)" ::: "memory");
        }
        __builtin_amdgcn_sched_barrier(0);
        __builtin_amdgcn_s_barrier();
        __builtin_amdgcn_sched_barrier(0);

        f32x4 acc_s[8] = {};
        __builtin_amdgcn_s_setprio(1);
        #pragma unroll
        for (int c = 0; c < 8; ++c) {
            int row = c * 16 + l15;
            const char* kb_ = (const char*)Ks[buf] + row * 128;
            int swz = (row & 7) << 4;
            bf16x8 kf0 = *(const bf16x8*)(kb_ + ((l16 * 16) ^ swz));
            bf16x8 kf1 = *(const bf16x8*)(kb_ + ((64 + l16 * 16) ^ swz));
            acc_s[c] = __builtin_amdgcn_mfma_f32_16x16x32_bf16(qf0, kf0, acc_s[c], 0, 0, 0);
            acc_s[c] = __builtin_amdgcn_mfma_f32_16x16x32_bf16(qf1, kf1, acc_s[c], 0, 0, 0);
        }
        __builtin_amdgcn_s_setprio(0);

        bool domask = CAUSAL && (it == n_tiles - 1);
        #pragma unroll
        for (int r = 0; r < 4; ++r) {
            float sc[8];
            #pragma unroll
            for (int c = 0; c < 8; ++c) {
                float s = acc_s[c][r];
                if (domask && (s0 + c * 16 + l15) > (t0 + w * 16 + l16 * 4 + r)) s = -1e30f;
                sc[c] = s;
            }
            float tm = fmaxf(fmaxf(fmaxf(sc[0], sc[1]), fmaxf(sc[2], sc[3])),
                             fmaxf(fmaxf(sc[4], sc[5]), fmaxf(sc[6], sc[7])));
            tm = fmaxf(tm, __shfl_xor(tm, 1, 16));
            tm = fmaxf(tm, __shfl_xor(tm, 2, 16));
            tm = fmaxf(tm, __shfl_xor(tm, 4, 16));
            tm = fmaxf(tm, __shfl_xor(tm, 8, 16));
            float mn = fmaxf(m_run[r], tm);
            int prow = l16 * 4 + r;
            int pswzr = prow << 4;
            float ls = 0.f;
            #pragma unroll
            for (int c = 0; c < 8; ++c) {
                float pv = __expf(0.125f * (sc[c] - mn));
                int pbyte = prow * 256 + (((c * 16 + l15) * 2) ^ pswzr);
                *(__hip_bfloat16*)(Pw + pbyte) = __float2bfloat16(pv);
                ls += pv;
            }
            ls += __shfl_xor(ls, 1, 16);
            ls += __shfl_xor(ls, 2, 16);
            ls += __shfl_xor(ls, 4, 16);
            ls += __shfl_xor(ls, 8, 16);
            float alpha = __expf(0.125f * (m_run[r] - mn));
            l_run[r] = l_run[r] * alpha + ls;
            m_run[r] = mn;
            acc_o[0][r] *= alpha; acc_o[1][r] *= alpha;
            acc_o[2][r] *= alpha; acc_o[3][r] *= alpha;
        }

        const char* Pb = Pw + l15 * 256;
        bf16x8 pa[4];
        #pragma unroll
        for (int tt = 0; tt < 4; ++tt)
            pa[tt] = *(const bf16x8*)(Pb + ((tt * 64 + l16 * 16) ^ pswz));
        __builtin_amdgcn_s_setprio(1);
        #pragma unroll
        for (int ni = 0; ni < 4; ++ni) {
            int row = ni * 16 + l15;
            const char* vb_ = (const char*)Vs[buf] + row * 256;
            int swz = (row & 15) << 4;
            #pragma unroll
            for (int tt = 0; tt < 4; ++tt) {
                bf16x8 vf = *(const bf16x8*)(vb_ + ((tt * 64 + l16 * 16) ^ swz));
                acc_o[ni] = __builtin_amdgcn_mfma_f32_16x16x32_bf16(pa[tt], vf, acc_o[ni], 0, 0, 0);
            }
        }
        __builtin_amdgcn_s_setprio(0);
        __builtin_amdgcn_s_barrier();
        __builtin_amdgcn_sched_barrier(0);
    }

    float inv[4];
    #pragma unroll
    for (int r = 0; r < 4; ++r) inv[r] = 1.0f / l_run[r];
    #pragma unroll
    for (int ni = 0; ni < 4; ++ni) {
        #pragma unroll
        for (int r = 0; r < 4; ++r) {
            size_t orow = ((size_t)(bI * T) + t0 + w * 16 + l16 * 4 + r) * D
                        + h * HS + ni * 16 + l15;
            att[orow] = __float2bfloat16(acc_o[ni][r] * inv[r]);
        }
    }
}

// ---------------------------------------------------------------------------
extern "C" void kernel_launch(void* const* d_in, const int* in_sizes, int n_in,
                              void* d_out, int out_size, void* d_ws, size_t ws_size,
                              hipStream_t stream) {
    const int*   idx     = (const int*)d_in[0];
    const float* tok_emb = (const float*)d_in[1];
    const float* pos_emb = (const float*)d_in[2];
    const float* Wq_u = (const float*)d_in[3],  *bq_u = (const float*)d_in[4];
    const float* Wk_u = (const float*)d_in[5],  *bk_u = (const float*)d_in[6];
    const float* Wv_u = (const float*)d_in[7],  *bv_u = (const float*)d_in[8];
    const float* Wp_u = (const float*)d_in[9],  *bp_u = (const float*)d_in[10];
    const float* Wq_m = (const float*)d_in[11], *bq_m = (const float*)d_in[12];
    const float* Wk_m = (const float*)d_in[13], *bk_m = (const float*)d_in[14];
    const float* Wv_m = (const float*)d_in[15], *bv_m = (const float*)d_in[16];
    const float* Wp_m = (const float*)d_in[17], *bp_m = (const float*)d_in[18];
    const float* W1   = (const float*)d_in[19], *b1   = (const float*)d_in[20];
    const float* W2   = (const float*)d_in[21], *b2   = (const float*)d_in[22];
    const float* lnf_g = (const float*)d_in[23], *lnf_b = (const float*)d_in[24];
    const float* n1_g  = (const float*)d_in[25], *n1_b  = (const float*)d_in[26];
    const float* n2_g  = (const float*)d_in[27], *n2_b  = (const float*)d_in[28];
    const float* nf_g  = (const float*)d_in[29], *nf_b  = (const float*)d_in[30];
    const float* Wfin  = (const float*)d_in[31], *bfin  = (const float*)d_in[32];
    float* out = (float*)d_out;

    char* p = (char*)d_ws;
    auto alloc = [&](size_t bytes) { char* r = p; p += (bytes + 255) & ~255ull; return r; };
    float* x    = (float*)alloc((size_t)M * D * 4);
    float* x2   = (float*)alloc((size_t)M * D * 4);
    unsigned short* w2p = (unsigned short*)alloc((size_t)4 * M * D * 2);  // bf16 partials
    short* qbf  = (short*)alloc((size_t)M * D * 2);
    short* kbf  = (short*)alloc((size_t)M * D * 2);
    short* vbf  = (short*)alloc((size_t)M * D * 2);
    short* vtb  = (short*)alloc((size_t)M * D * 2);
    short* xnb  = (short*)alloc((size_t)M * D * 2);
    short* attb = (short*)alloc((size_t)M * D * 2);
    short* hb   = (short*)alloc((size_t)M * DFF * 2);
    short* WqkvT= (short*)alloc((size_t)2 * 3 * H * HS * D * 2);
    short* WpT  = (short*)alloc((size_t)2 * D * D * 2);
    short* W1T  = (short*)alloc((size_t)D * DFF * 2);
    short* W2T  = (short*)alloc((size_t)DFF * D * 2);
    short* WfT  = (short*)alloc((size_t)D * V * 2);

    embed_ln_kernel<<<M / 4, 256, 0, stream>>>(idx, tok_emb, pos_emb,
        n1_g, n1_b, x, (__hip_bfloat16*)xnb);
    transpose_bf16_kernel<<<dim3(V / 32, D / 32), 256, 0, stream>>>(
        Wfin, (__hip_bfloat16*)WfT, D, V);

    for (int l = 0; l < LNUM; ++l) {
        const float *n1g = n1_g + l * D, *n1b = n1_b + l * D;
        const float *n2g = n2_g + l * D, *n2b = n2_b + l * D;
        const float *lfg = lnf_g + l * D, *lfb = lnf_b + l * D;
        const float *W1l = W1 + (size_t)l * D * DFF, *b1l = b1 + l * DFF;
        const float *W2l = W2 + (size_t)l * DFF * D, *b2l = b2 + l * D;
        trans_w12_kernel<<<dim3(160, 32, 2), 256, 0, stream>>>(
            W1l, W2l, W1T, W2T);
        trans_qkvp2_kernel<<<dim3(32, 32, 8), 256, 0, stream>>>(
            Wq_u + (size_t)l * H * D * HS, Wk_u + (size_t)l * H * D * HS,
            Wv_u + (size_t)l * H * D * HS, Wp_u + (size_t)l * D * D,
            Wq_m + (size_t)l * H * D * HS, Wk_m + (size_t)l * H * D * HS,
            Wv_m + (size_t)l * H * D * HS, Wp_m + (size_t)l * D * D,
            WqkvT, WpT);
        for (int half = 0; half < 2; ++half) {
            const float *bq_, *bk_, *bv_, *bp_;
            if (half == 0) { bq_ = bq_u; bk_ = bk_u; bv_ = bv_u; bp_ = bp_u; }
            else           { bq_ = bq_m; bk_ = bk_m; bv_ = bv_m; bp_ = bp_m; }
            bq_ += l * H * HS;  bk_ += l * H * HS;  bv_ += l * H * HS;  bp_ += l * D;
            const short* WqkvTh = WqkvT + (size_t)half * 3 * H * HS * D;
            const short* WpTh   = WpT + (size_t)half * D * D;

            // q,k,v = xn @ Wqkv -> bf16 [B,H,T,HS]
            mm_bf16_kernel<128, 3><<<dim3(M / 128, 3072 / 128), 256, 0, stream>>>(
                xnb, WqkvTh, bq_, bk_, bv_, nullptr,
                (float*)qbf, (float*)kbf, (float*)vbf, nullptr, 3072, D, D);
            transpose_v_kernel<<<dim3(HS / 32, T / 32, BB * H), 256, 0, stream>>>(vbf, vtb);
            if (half == 0)
                attn_mfma_kernel<0><<<dim3(T / 64, BB * H), 256, 0, stream>>>(
                    qbf, kbf, vtb, (__hip_bfloat16*)attb);
            else
                attn_mfma_kernel<1><<<dim3(T / 64, BB * H), 256, 0, stream>>>(
                    qbf, kbf, vtb, (__hip_bfloat16*)attb);
            // att @ Wp  split-K x2 -> bf16 partials (512 blocks)
            mm_bf16_kernel<64, 5><<<dim3(M / 64, D / 128, 2), 256, 0, stream>>>(
                attb, WpTh, nullptr, nullptr, nullptr, nullptr, nullptr, nullptr, nullptr,
                (__hip_bfloat16*)w2p, D, D / 2, D);
            // proj tail: x2 = x + p0 + p1 + bp ; xn = ln(x2, n2)
            proj_tail_kernel<<<M / 4, 256, 0, stream>>>(
                w2p, bp_, x, n2g, n2b, x2, (__hip_bfloat16*)xnb);
            // h = leaky(xn @ W1 + b1) -> bf16  (256^2 2-phase)
            mm256_kernel<2><<<(M / 256) * (DFF / 256), 512, 0, stream>>>(
                xnb, W1T, b1l, nullptr, (__hip_bfloat16*)hb, DFF, D, D);
            // W2 split-K x4 -> bf16 partials (512 blocks, 2/CU)
            mm_bf16_kernel<128, 5><<<dim3(M / 128, D / 128, 4), 256, 0, stream>>>(
                hb, W2T, nullptr, nullptr, nullptr, nullptr, nullptr, nullptr, nullptr,
                (__hip_bfloat16*)w2p, D, DFF / 4, DFF);
            const float* og = half ? n2g : n1g;
            const float* ob = half ? n2b : n1b;
            const float* gn; const float* bn;
            if (half == 0)      { gn = n1g; bn = n1b; }
            else if (l < LNUM-1){ gn = n1_g + (l+1)*D; bn = n1_b + (l+1)*D; }
            else                { gn = nf_g; bn = nf_b; }
            ffn_tail_kernel<4><<<M / 4, 256, 0, stream>>>(
                w2p, b2l, lfg, lfb, og, ob, x2, x, gn, bn, (__hip_bfloat16*)xnb);
        }
    }
    // vocab head
    mm256_kernel<0><<<(M / 256) * (V / 256), 512, 0, stream>>>(
        xnb, WfT, bfin, out, nullptr, V, D, D);
}